// Round 12
// baseline (502.853 us; speedup 1.0000x reference)
//
#include <hip/hip_runtime.h>
#include <hip/hip_bf16.h>

typedef unsigned short u16;
typedef unsigned int   u32;
typedef short bf16x8 __attribute__((ext_vector_type(8)));
typedef float f32x4  __attribute__((ext_vector_type(4)));

__device__ __forceinline__ float b2f(u16 u) {
    return __uint_as_float(((u32)u) << 16);
}
__device__ __forceinline__ u16 f2b(float f) {
    __hip_bfloat16 h = __float2bfloat16(f);
    u16 r; __builtin_memcpy(&r, &h, 2); return r;
}
// dtype-adaptive input load / output store (flag: 1 = fp32, 0 = bf16)
__device__ __forceinline__ float ldin(const void* p, size_t i, bool f32) {
    return f32 ? ((const float*)p)[i] : b2f(((const u16*)p)[i]);
}
__device__ __forceinline__ void stout(void* p, size_t i, float v, bool f32) {
    if (f32) ((float*)p)[i] = v; else ((u16*)p)[i] = f2b(v);
}

// ---------------------------------------------------------------------------
// K-1: dtype detector (fp32 low halves ~ uniform bits -> bf16-NaN patterns).
// ---------------------------------------------------------------------------
__global__ __launch_bounds__(256) void k_detect(const void* __restrict__ xraw, int* __restrict__ flag)
{
    const uint4* xv = (const uint4*)xraw;
    int t = threadIdx.x;
    int cnt = 0;
    for (int i = t; i < 8192; i += 256) {
        uint4 u = xv[i];
        u32 uu[4] = {u.x, u.y, u.z, u.w};
        #pragma unroll
        for (int q = 0; q < 4; ++q) {
            u16 a = (u16)(uu[q] & 0xffff), b = (u16)(uu[q] >> 16);
            if ((a & 0x7F80u) == 0x7F80u && (a & 0x007Fu) != 0) cnt++;
            if ((b & 0x7F80u) == 0x7F80u && (b & 0x007Fu) != 0) cnt++;
        }
    }
    __shared__ int red[256];
    red[t] = cnt; __syncthreads();
    for (int st = 128; st > 0; st >>= 1) {
        if (t < st) red[t] += red[t + st];
        __syncthreads();
    }
    if (t == 0) flag[0] = (red[0] > 16) ? 1 : 0;
}

// ---------------------------------------------------------------------------
// K0: pooled offset lines (dX, dY) + regloss.  offsets [2][131][131]
// ---------------------------------------------------------------------------
__global__ __launch_bounds__(256) void k_setup(const void* __restrict__ off,
                                               float* __restrict__ dX, float* __restrict__ dY,
                                               void* __restrict__ out, const int* __restrict__ flag) {
    bool f32 = flag[0] != 0;
    int t = threadIdx.x;
    if (t < 129) {
        for (int ch = 0; ch < 2; ++ch) {
            float s1 = 0.f, s2 = 0.f;
            for (int i = 0; i < 3; ++i)
                for (int j = 0; j < 3; ++j) {
                    s1 += ldin(off, ch*17161 + (t+i)*131 + (64+j), f32);
                    s2 += ldin(off, ch*17161 + (64+i)*131 + (t+j), f32);
                }
            dX[t*2 + ch] = s1 * (1.0f/9.0f);
            dY[t*2 + ch] = s2 * (1.0f/9.0f);
        }
    }
    float s = 0.f;
    for (int idx = t; idx < 17161; idx += 256) {
        float d = ldin(off, idx, f32) - ldin(off, 17161 + idx, f32);
        s += d * d * (1.0f/17161.0f);
    }
    for (int idx = t; idx < 34060; idx += 256) {
        int ch = idx / 17030;
        int rem = idx - ch*17030;
        int r = rem / 131, c = rem - r*131;
        float a = ldin(off, ch*17161 + r*131 + c, f32);
        float b = ldin(off, ch*17161 + (r+1)*131 + c, f32);
        float d = a - b;
        s += d * d * (1.0f/34060.0f);
    }
    __shared__ float red[256];
    red[t] = s; __syncthreads();
    for (int st = 128; st > 0; st >>= 1) {
        if (t < st) red[t] += red[t + st];
        __syncthreads();
    }
    if (t == 0) {
        float v = red[0];
        if (!(v == v)) v = -299.f;
        stout(out, (size_t)16777216, v, f32);
    }
}

// ---------------------------------------------------------------------------
// K0b: weight conversion, ONCE.  W rows stacked [Wq(32) | Wk(32) | Wv(256)]
// -> WH/WLo bf16 [320][256], bias fp32 [320].
// ---------------------------------------------------------------------------
__global__ __launch_bounds__(256) void k_wconv(
    const void* __restrict__ Wq, const void* __restrict__ Wk, const void* __restrict__ Wv,
    const void* __restrict__ bq, const void* __restrict__ bk, const void* __restrict__ bv,
    u16* __restrict__ WH, u16* __restrict__ WLo, float* __restrict__ bias,
    const int* __restrict__ flag)
{
    bool f32 = flag[0] != 0;
    int idx = blockIdx.x * 256 + threadIdx.x;          // grid 320 -> 81920
    if (idx < 81920) {
        int row = idx >> 8;
        int col = idx & 255;
        const void* src; int r;
        if (row < 32)      { src = Wq; r = row; }
        else if (row < 64) { src = Wk; r = row - 32; }
        else               { src = Wv; r = row - 64; }
        float wv = ldin(src, (size_t)r*256 + col, f32);
        u16 hi = f2b(wv);
        WH [idx] = hi;
        WLo[idx] = f2b(wv - b2f(hi));
    }
    if (blockIdx.x == 0 && threadIdx.x < 320) {
        int row = threadIdx.x;
        const void* src; int r;
        if (row < 32)      { src = bq; r = row; }
        else if (row < 64) { src = bk; r = row - 32; }
        else               { src = bv; r = row - 64; }
        bias[row] = ldin(src, r, f32);
    }
}

// ---------------------------------------------------------------------------
// K0c: x transpose+convert, ONCE.  x [B][C][HW] (f32 or bf16)
// -> xb bf16 [B*HW][256] (pixel-major, channel-fast).
// ---------------------------------------------------------------------------
__global__ __launch_bounds__(256) void k_xconv(const void* __restrict__ xraw,
                                               u16* __restrict__ xb,
                                               const int* __restrict__ flag)
{
    bool f32 = flag[0] != 0;
    int t = threadIdx.x;
    int bidx = blockIdx.x;                   // 0..511
    int b  = bidx >> 7;
    int p0 = (bidx & 127) * 128;
    int p  = p0 + (t & 127);
    int ch0 = blockIdx.y * 128 + (t >> 7) * 64;
    size_t xbase = ((size_t)b * 256) * 16384 + p;      // + c*16384
    u16* dst = xb + ((size_t)(b*16384 + p)) * 256 + ch0;
    for (int oct = 0; oct < 8; ++oct) {
        u32 w[4];
        #pragma unroll
        for (int q = 0; q < 4; ++q) {
            int c = ch0 + oct*8 + q*2;
            u16 lo, hi;
            if (f32) {
                const float* xf = (const float*)xraw;
                lo = f2b(xf[xbase + (size_t)c*16384]);
                hi = f2b(xf[xbase + (size_t)(c+1)*16384]);
            } else {
                const u16* xu = (const u16*)xraw;
                lo = xu[xbase + (size_t)c*16384];
                hi = xu[xbase + (size_t)(c+1)*16384];
            }
            w[q] = (u32)lo | ((u32)hi << 16);
        }
        *reinterpret_cast<uint4*>(dst + oct*8) = make_uint4(w[0], w[1], w[2], w[3]);
    }
}

// ---------------------------------------------------------------------------
// K1: MFMA projections, ot-FUSED, 128 px per block (512 blocks, 2 blocks/CU).
// All 5 output slices per block: xb fragments loaded ONCE (reused 5x, 64 VGPR),
// every pqk/pvx row written entirely by one block (full-line merge).
// (256,2): 2 waves/SIMD so co-resident blocks hide each other's weight-load
// latency (R11's 1-wave/SIMD variant had zero TLP -> 73us despite min traffic).
// ---------------------------------------------------------------------------
__global__ __launch_bounds__(256, 2) void k_proj_mfma(
    const u16* __restrict__ xb,
    const u16* __restrict__ WH, const u16* __restrict__ WLo,
    const float* __restrict__ bias,
    u16* __restrict__ pqk, u16* __restrict__ pvx)
{
    int t = threadIdx.x;
    int gp = blockIdx.x * 128;           // global pixel base (b*16384 + p0)
    int b  = gp >> 14;
    int p0 = gp & 16383;

    int wid = t >> 6, lane = t & 63;
    int quad = lane >> 4, n = lane & 15;

    const u16* xr = xb + ((size_t)(gp + wid*32 + n)) * 256 + quad*8;

    // preload this lane's full xb slice (16 x dwordx4 = 64 VGPR) — read ONCE
    bf16x8 bf[8][2];
    #pragma unroll
    for (int kc = 0; kc < 8; ++kc)
        #pragma unroll
        for (int pt = 0; pt < 2; ++pt)
            bf[kc][pt] = *reinterpret_cast<const bf16x8*>(xr + (size_t)pt*16*256 + kc*32);

    for (int ot = 0; ot < 5; ++ot) {
        int o_base = ot * 64;
        const u16* whp = WH  + ((size_t)(o_base + n)) * 256 + quad*8;
        const u16* wlp = WLo + ((size_t)(o_base + n)) * 256 + quad*8;

        f32x4 acc[4][2];
        #pragma unroll
        for (int i = 0; i < 4; ++i)
            #pragma unroll
            for (int j = 0; j < 2; ++j) acc[i][j] = (f32x4){0.f, 0.f, 0.f, 0.f};

        #pragma unroll
        for (int kc = 0; kc < 8; ++kc) {
            int c0 = kc * 32;
            #pragma unroll
            for (int ot2 = 0; ot2 < 4; ++ot2) {
                bf16x8 ah = *reinterpret_cast<const bf16x8*>(whp + (size_t)ot2*16*256 + c0);
                bf16x8 al = *reinterpret_cast<const bf16x8*>(wlp + (size_t)ot2*16*256 + c0);
                #pragma unroll
                for (int pt = 0; pt < 2; ++pt) {
                    acc[ot2][pt] = __builtin_amdgcn_mfma_f32_16x16x32_bf16(ah, bf[kc][pt], acc[ot2][pt], 0, 0, 0);
                    acc[ot2][pt] = __builtin_amdgcn_mfma_f32_16x16x32_bf16(al, bf[kc][pt], acc[ot2][pt], 0, 0, 0);
                }
            }
        }
        #pragma unroll
        for (int ot2 = 0; ot2 < 4; ++ot2) {
            int o_l = ot2*16 + quad*4;
            int og  = o_base + o_l;
            float b0 = bias[og], b1 = bias[og+1], b2 = bias[og+2], b3 = bias[og+3];
            #pragma unroll
            for (int pt = 0; pt < 2; ++pt) {
                f32x4 a = acc[ot2][pt];
                int px = p0 + wid*32 + pt*16 + n;
                u32 w0 = (u32)f2b(a[0] + b0) | ((u32)f2b(a[1] + b1) << 16);
                u32 w1 = (u32)f2b(a[2] + b2) | ((u32)f2b(a[3] + b3) << 16);
                u16* dst;
                if (ot == 0) dst = pqk + ((size_t)(b*16384 + px))*64  + o_l;
                else         dst = pvx + ((size_t)(b*16384 + px))*256 + (o_base - 64 + o_l);
                *reinterpret_cast<uint2*>(dst) = make_uint2(w0, w1);
            }
        }
    }
}

// ---------------------------------------------------------------------------
// K1b: transpose k-half of pqk into col-major pkc[B][W][H][32]  (b>=1 only).
// ---------------------------------------------------------------------------
__global__ __launch_bounds__(256) void k_transqk(const u16* __restrict__ pqk, u16* __restrict__ pkc)
{
    int pg = 16384 + blockIdx.x*256 + threadIdx.x;
    int b = pg >> 14, hw = pg & 16383, h = hw >> 7, w = hw & 127;
    const uint4* src = reinterpret_cast<const uint4*>(pqk + (size_t)pg*64 + 32);
    uint4* dst = reinterpret_cast<uint4*>(pkc + (((size_t)(b*128 + w))*128 + h)*32);
    #pragma unroll
    for (int i = 0; i < 4; ++i) dst[i] = src[i];
}

// ---------------------------------------------------------------------------
// K1c: transpose pvx into col-major pvc[B][W][H][256]  (b>=1 only).
// ---------------------------------------------------------------------------
__global__ __launch_bounds__(256) void k_transv(const u16* __restrict__ pvx, u16* __restrict__ pvc)
{
    int t = threadIdx.x;
    int p = 16384 + blockIdx.x*8 + (t >> 5);
    int c = (t & 31)*8;
    int b = p >> 14, hw = p & 16383, h = hw >> 7, w = hw & 127;
    *reinterpret_cast<uint4*>(pvc + (((size_t)(b*128 + w))*128 + h)*256 + c) =
        *reinterpret_cast<const uint4*>(pvx + (size_t)p*256 + c);
}

// ---------------------------------------------------------------------------
// K2: deformed bilinear sampling for batch 0.
// ---------------------------------------------------------------------------
__global__ __launch_bounds__(320) void k_sample(
    const u16* __restrict__ pqk, const u16* __restrict__ pvx,
    const float* __restrict__ dX, const float* __restrict__ dY,
    u16* __restrict__ qdH, u16* __restrict__ pkc, u16* __restrict__ pvc,
    u16* __restrict__ qdW, u16* __restrict__ kdW, u16* __restrict__ vdW)
{
    int bid = blockIdx.x;
    int variant = bid >> 14;
    int pt = bid & 16383;
    int t = threadIdx.x;
    int w, h;
    float xn, yn;
    if (variant == 0) {
        w = pt >> 7; h = pt & 127;
        xn = (-1.0f + (float)w     * (2.0f/128.0f)) + dX[(h+1)*2 + 0];
        yn = (-1.0f + (float)(h+1) * (2.0f/128.0f)) + dX[(h+1)*2 + 1];
    } else {
        h = pt >> 7; w = pt & 127;
        xn = (-1.0f + (float)(w+1) * (2.0f/128.0f)) + dY[(w+1)*2 + 0];
        yn = (-1.0f + (float)h     * (2.0f/128.0f)) + dY[(w+1)*2 + 1];
    }
    float fx = (xn + 1.0f) * 0.5f * 127.0f;
    float fy = (yn + 1.0f) * 0.5f * 127.0f;
    float x0f = floorf(fx), y0f = floorf(fy);
    float wx = fx - x0f, wy = fy - y0f;

    float wt[4]; int xi[4], yi[4]; bool vd[4];
    {
        float xs[2]  = { x0f, x0f + 1.0f };
        float ys[2]  = { y0f, y0f + 1.0f };
        float wxs[2] = { 1.0f - wx, wx };
        float wys[2] = { 1.0f - wy, wy };
        #pragma unroll
        for (int jy = 0; jy < 2; ++jy)
            #pragma unroll
            for (int jx = 0; jx < 2; ++jx) {
                int k = jy*2 + jx;
                vd[k] = (xs[jx] >= 0.f) && (xs[jx] < 128.f) && (ys[jy] >= 0.f) && (ys[jy] < 128.f);
                wt[k] = wxs[jx] * wys[jy];
                xi[k] = (int)fminf(fmaxf(xs[jx], 0.f), 127.f);
                yi[k] = (int)fminf(fmaxf(ys[jy], 0.f), 127.f);
            }
    }
    float val = 0.f;
    if (t < 64) {
        #pragma unroll
        for (int k = 0; k < 4; ++k)
            if (vd[k]) val += wt[k] * b2f(pqk[(size_t)(yi[k]*128 + xi[k])*64 + t]);
        if (t < 32) {
            if (variant == 0) qdH[(size_t)pt*32 + t] = f2b(val);
            else              qdW[(size_t)pt*32 + t] = f2b(val);
        } else {
            int c = t - 32;
            if (variant == 0) pkc[(size_t)pt*32 + c] = f2b(val);
            else              kdW[(size_t)pt*32 + c] = f2b(val);
        }
    } else {
        int c = t - 64;
        #pragma unroll
        for (int k = 0; k < 4; ++k)
            if (vd[k]) val += wt[k] * b2f(pvx[(size_t)(yi[k]*128 + xi[k])*256 + c]);
        if (variant == 0) pvc[(size_t)pt*256 + c] = f2b(val);
        else              vdW[(size_t)pt*256 + c] = f2b(val);
    }
}

// ---------------------------------------------------------------------------
// K3a: raw attention scores via MFMA.  1024 blocks = kind(2) x b(4) x line(128).
// SH -> T-alias f32; SW rows live inside attbH/attbW bytes (f32) — see launch.
// ---------------------------------------------------------------------------
__global__ __launch_bounds__(256) void k_scores(
    const u16* __restrict__ pqk, const u16* __restrict__ pkc,
    const u16* __restrict__ qdH, const u16* __restrict__ qdW, const u16* __restrict__ kdW,
    float* __restrict__ SH, float* __restrict__ SWa, float* __restrict__ SWb)
{
    int bid = blockIdx.x;
    int kind = bid >> 9;
    int b    = (bid >> 7) & 3;
    int line = bid & 127;
    int t = threadIdx.x;
    int wid = t >> 6, lane = t & 63;
    int n16 = lane & 15, quad = lane >> 4;

    const u16 *Qb, *Kb; int qstride, kstride;
    float* Sb = nullptr;
    float* s_lo = nullptr; float* s_hi = nullptr;
    if (kind == 0) {                 // column scores, line = w
        if (b == 0) { Qb = qdH + (size_t)line*4096;                 qstride = 32;   }
        else        { Qb = pqk + ((size_t)(b*16384 + line))*64;     qstride = 8192; }
        Kb = pkc + ((size_t)(b*128 + line))*4096;                   kstride = 32;
        Sb = SH + ((size_t)(b*128 + line))*16384;
    } else {                          // row scores, line = h
        if (b == 0) { Qb = qdW + (size_t)line*4096;                 qstride = 32;
                      Kb = kdW + (size_t)line*4096;                 kstride = 32; }
        else        { Qb = pqk + ((size_t)(b*16384 + line*128))*64; qstride = 64;
                      Kb = Qb + 32;                                 kstride = 64; }
        size_t base = (size_t)(b*128 + line)*8192;
        s_lo = SWa + base;            // rows 0..63
        s_hi = SWb + base;            // rows 64..127 (index m-64)
    }

    bf16x8 af[2];
    #pragma unroll
    for (int m2 = 0; m2 < 2; ++m2)
        af[m2] = *reinterpret_cast<const bf16x8*>(
            Qb + (size_t)(wid*32 + m2*16 + n16)*qstride + quad*8);

    #pragma unroll
    for (int nt = 0; nt < 8; ++nt) {
        bf16x8 bf = *reinterpret_cast<const bf16x8*>(
            Kb + (size_t)(nt*16 + n16)*kstride + quad*8);
        f32x4 a0 = (f32x4){0.f,0.f,0.f,0.f};
        f32x4 a1 = (f32x4){0.f,0.f,0.f,0.f};
        a0 = __builtin_amdgcn_mfma_f32_16x16x32_bf16(af[0], bf, a0, 0, 0, 0);
        a1 = __builtin_amdgcn_mfma_f32_16x16x32_bf16(af[1], bf, a1, 0, 0, 0);
        int j = nt*16 + n16;
        int m0 = wid*32 + quad*4;
        if (kind == 0) {
            #pragma unroll
            for (int r = 0; r < 4; ++r) {
                Sb[(size_t)(m0 + r)*128 + j]      = a0[r];
                Sb[(size_t)(m0 + 16 + r)*128 + j] = a1[r];
            }
        } else {
            #pragma unroll
            for (int r = 0; r < 4; ++r) {
                int mA = m0 + r, mB = m0 + 16 + r;
                float* pA = (mA < 64) ? (s_lo + (size_t)mA*128 + j)
                                      : (s_hi + (size_t)(mA - 64)*128 + j);
                float* pB = (mB < 64) ? (s_lo + (size_t)mB*128 + j)
                                      : (s_hi + (size_t)(mB - 64)*128 + j);
                *pA = a0[r];
                *pB = a1[r];
            }
        }
    }
}

// ---------------------------------------------------------------------------
// K3b: joint softmax, register-resident.  block (b,h), 256 thr = (kind, w).
// ---------------------------------------------------------------------------
__global__ __launch_bounds__(256) void k_softmax(
    const float* __restrict__ SH, const float* __restrict__ SWa, const float* __restrict__ SWb,
    u16* __restrict__ attbH, u16* __restrict__ attbW)
{
    int b = blockIdx.x >> 7, h = blockIdx.x & 127;
    int t = threadIdx.x;
    int kind = t >> 7, w = t & 127;
    __shared__ float mh[256], zh[256];
    __shared__ float Mw[128], Iw[128];

    const float* src;
    if (kind == 0) {
        src = SH + (((size_t)(b*128 + w))*128 + h)*128;
    } else {
        size_t base = (size_t)(b*128 + h)*8192;
        src = (w < 64) ? (SWa + base + (size_t)w*128)
                       : (SWb + base + (size_t)(w - 64)*128);
    }
    const float4* s4 = reinterpret_cast<const float4*>(src);

    float4 row[32];
    #pragma unroll
    for (int q = 0; q < 32; ++q) row[q] = s4[q];

    if (kind == 0) {
        #pragma unroll
        for (int q = 0; q < 32; ++q) {
            float4 v = row[q];
            if (q*4     == h) v.x = -INFINITY;
            if (q*4 + 1 == h) v.y = -INFINITY;
            if (q*4 + 2 == h) v.z = -INFINITY;
            if (q*4 + 3 == h) v.w = -INFINITY;
            row[q] = v;
        }
    }

    float m = -INFINITY;
    #pragma unroll
    for (int q = 0; q < 32; ++q) {
        float4 v = row[q];
        m = fmaxf(m, fmaxf(fmaxf(v.x, v.y), fmaxf(v.z, v.w)));
    }
    mh[t] = m;
    __syncthreads();
    if (t < 128) Mw[t] = fmaxf(mh[t], mh[128 + t]);
    __syncthreads();

    float M = Mw[w];
    float Z = 0.f;
    #pragma unroll
    for (int q = 0; q < 32; ++q) {
        float4 v = row[q];
        Z += __expf(v.x - M) + __expf(v.y - M) + __expf(v.z - M) + __expf(v.w - M);
    }
    zh[t] = Z;
    __syncthreads();
    if (t < 128) Iw[t] = 1.0f / (zh[t] + zh[128 + t]);
    __syncthreads();

    float I = Iw[w];
    u16* dst = (kind == 0)
        ? attbH + (((size_t)(b*128 + h))*128 + w)*128
        : attbW + (((size_t)(b*128 + h))*128 + w)*128;
    #pragma unroll
    for (int q = 0; q < 16; ++q) {
        float4 v0 = row[2*q], v1 = row[2*q + 1];
        u32 o0 = (u32)f2b(__expf(v0.x - M) * I) | ((u32)f2b(__expf(v0.y - M) * I) << 16);
        u32 o1 = (u32)f2b(__expf(v0.z - M) * I) | ((u32)f2b(__expf(v0.w - M) * I) << 16);
        u32 o2 = (u32)f2b(__expf(v1.x - M) * I) | ((u32)f2b(__expf(v1.y - M) * I) << 16);
        u32 o3 = (u32)f2b(__expf(v1.z - M) * I) | ((u32)f2b(__expf(v1.w - M) * I) << 16);
        *reinterpret_cast<uint4*>(dst + q*8) = make_uint4(o0, o1, o2, o3);
    }
}

// ---------------------------------------------------------------------------
// LDS V-transpose staging shared by K4/K5:
// vt[c][m] = pack(V[2m][c], V[2m+1][c]) as u32, row stride 68 u32.
// ---------------------------------------------------------------------------
__device__ __forceinline__ void stage_vt(u32* vt, const u16* Vsrc, int t)
{
    int j2 = t & 63;                 // row pair index
    int c8 = (t >> 6) * 8;           // col octet base
    const u16* r0 = Vsrc + (size_t)(2*j2)*256;
    const u16* r1 = r0 + 256;
    #pragma unroll
    for (int i = 0; i < 4; ++i) {
        int c = i*32 + c8;
        uint4 a  = *reinterpret_cast<const uint4*>(r0 + c);
        uint4 bb = *reinterpret_cast<const uint4*>(r1 + c);
        u32 au[4] = {a.x, a.y, a.z, a.w};
        u32 bu[4] = {bb.x, bb.y, bb.z, bb.w};
        #pragma unroll
        for (int e = 0; e < 4; ++e) {
            vt[(c + 2*e    )*68 + j2] = (au[e] & 0xffffu) | (bu[e] << 16);
            vt[(c + 2*e + 1)*68 + j2] = (au[e] >> 16)     | (bu[e] & 0xffff0000u);
        }
    }
}

// ---------------------------------------------------------------------------
// K4: column aggregation via MFMA, V via LDS transpose (1 ds_read_b128/frag).
// T[b][w][k][c] = sum_h attbH[b,k,w,h] * pvc[b,w,h,c]
// ---------------------------------------------------------------------------
__global__ __launch_bounds__(256, 2) void k_outcol(const u16* __restrict__ pvc,
    const u16* __restrict__ attbH, u16* __restrict__ T)
{
    int b = blockIdx.x >> 7, w = blockIdx.x & 127;
    int half = blockIdx.y;
    int t = threadIdx.x;
    int wid = t >> 6, lane = t & 63;
    int n16 = lane & 15, quad = lane >> 4;

    __shared__ u32 vt[128*68];

    const u16* Abase = attbH + ((size_t)b*128)*16384 + (size_t)w*128;
    bf16x8 af[2][4];
    #pragma unroll
    for (int m2 = 0; m2 < 2; ++m2)
        #pragma unroll
        for (int ks = 0; ks < 4; ++ks)
            af[m2][ks] = *reinterpret_cast<const bf16x8*>(
                Abase + (size_t)(wid*32 + m2*16 + n16)*16384 + ks*32 + quad*8);

    stage_vt(vt, pvc + (((size_t)(b*128 + w))*128)*256 + half*128, t);
    __syncthreads();

    f32x4 acc[2][8];
    #pragma unroll
    for (int m2 = 0; m2 < 2; ++m2)
        #pragma unroll
        for (int nt = 0; nt < 8; ++nt) acc[m2][nt] = (f32x4){0.f,0.f,0.f,0.f};

    #pragma unroll
    for (int nt = 0; nt < 8; ++nt) {
        int c = nt*16 + n16;
        #pragma unroll
        for (int ks = 0; ks < 4; ++ks) {
            bf16x8 bfv = *reinterpret_cast<const bf16x8*>(&vt[c*68 + ks*16 + quad*4]);
            acc[0][nt] = __builtin_amdgcn_mfma_f32_16x16x32_bf16(af[0][ks], bfv, acc[0][nt], 0, 0, 0);
            acc[1][nt] = __builtin_amdgcn_mfma_f32_16x16x32_bf16(af[1][ks], bfv, acc[1][nt], 0, 0, 0);
        }
    }

    u16* Tbase = T + (((size_t)(b*128 + w))*128)*256 + half*128;
    #pragma unroll
    for (int m2 = 0; m2 < 2; ++m2) {
        int k0 = wid*32 + m2*16 + quad*4;
        #pragma unroll
        for (int nt = 0; nt < 8; ++nt) {
            int c = nt*16 + n16;
            f32x4 a = acc[m2][nt];
            #pragma unroll
            for (int r = 0; r < 4; ++r)
                Tbase[(size_t)(k0 + r)*256 + c] = f2b(a[r]);
        }
    }
}

// ---------------------------------------------------------------------------
// K5: row aggregation via MFMA + epilogue, V via LDS transpose.
// ---------------------------------------------------------------------------
__global__ __launch_bounds__(256, 2) void k_outrow(const u16* __restrict__ pvx, const u16* __restrict__ vdW,
    const u16* __restrict__ attbW, const u16* __restrict__ T, const void* __restrict__ xraw,
    const void* __restrict__ gamma, void* __restrict__ out, const int* __restrict__ flag)
{
    bool f32 = flag[0] != 0;
    int b = blockIdx.x >> 7, h = blockIdx.x & 127;
    int half = blockIdx.y;
    int t = threadIdx.x;
    int wid = t >> 6, lane = t & 63;
    int n16 = lane & 15, quad = lane >> 4;

    __shared__ u32 vt[128*68];

    const u16* Abase = attbW + ((size_t)(b*128 + h))*16384;
    bf16x8 af[2][4];
    #pragma unroll
    for (int m2 = 0; m2 < 2; ++m2)
        #pragma unroll
        for (int ks = 0; ks < 4; ++ks)
            af[m2][ks] = *reinterpret_cast<const bf16x8*>(
                Abase + (size_t)(wid*32 + m2*16 + n16)*128 + ks*32 + quad*8);

    const u16* Vsrc = ((b == 0) ? (vdW + (size_t)h*128*256)
                                : (pvx + ((size_t)b*16384 + h*128)*256)) + half*128;
    stage_vt(vt, Vsrc, t);
    __syncthreads();

    f32x4 acc[2][8];
    #pragma unroll
    for (int m2 = 0; m2 < 2; ++m2)
        #pragma unroll
        for (int nt = 0; nt < 8; ++nt) acc[m2][nt] = (f32x4){0.f,0.f,0.f,0.f};

    #pragma unroll
    for (int nt = 0; nt < 8; ++nt) {
        int c = nt*16 + n16;
        #pragma unroll
        for (int ks = 0; ks < 4; ++ks) {
            bf16x8 bfv = *reinterpret_cast<const bf16x8*>(&vt[c*68 + ks*16 + quad*4]);
            acc[0][nt] = __builtin_amdgcn_mfma_f32_16x16x32_bf16(af[0][ks], bfv, acc[0][nt], 0, 0, 0);
            acc[1][nt] = __builtin_amdgcn_mfma_f32_16x16x32_bf16(af[1][ks], bfv, acc[1][nt], 0, 0, 0);
        }
    }

    float gm = ldin(gamma, 0, f32);
    const u16* Tbase = T + ((size_t)(b*128))*128*256 + (size_t)h*256 + half*128;

    #pragma unroll
    for (int m2 = 0; m2 < 2; ++m2) {
        int k0 = wid*32 + m2*16 + quad*4;
        #pragma unroll
        for (int nt = 0; nt < 8; ++nt) {
            int c = nt*16 + n16;
            int cg = half*128 + c;
            f32x4 a = acc[m2][nt];
            float r[4];
            #pragma unroll
            for (int i = 0; i < 4; ++i) {
                float hst = b2f(Tbase[(size_t)(k0 + i)*32768 + c]);
                r[i] = gm * (hst + a[i]);
            }
            size_t base = ((size_t)(b*256 + cg)*128 + h)*128 + k0;
            if (f32) {
                float4 xx = *reinterpret_cast<const float4*>((const float*)xraw + base);
                float4 rr;
                rr.x = r[0] + xx.x; rr.y = r[1] + xx.y;
                rr.z = r[2] + xx.z; rr.w = r[3] + xx.w;
                if (!(rr.x == rr.x)) rr.x = -299.f;
                if (!(rr.y == rr.y)) rr.y = -299.f;
                if (!(rr.z == rr.z)) rr.z = -299.f;
                if (!(rr.w == rr.w)) rr.w = -299.f;
                *reinterpret_cast<float4*>((float*)out + base) = rr;
            } else {
                uint2 xx = *reinterpret_cast<const uint2*>((const u16*)xraw + base);
                u32 xu[2] = { xx.x, xx.y };
                u32 ou[2];
                #pragma unroll
                for (int p2 = 0; p2 < 2; ++p2) {
                    float xlo = __uint_as_float(xu[p2] << 16);
                    float xhi = __uint_as_float(xu[p2] & 0xffff0000u);
                    float olo = r[p2*2]   + xlo;
                    float ohi = r[p2*2+1] + xhi;
                    if (!(olo == olo)) olo = -299.f;
                    if (!(ohi == ohi)) ohi = -299.f;
                    ou[p2] = (u32)f2b(olo) | ((u32)f2b(ohi) << 16);
                }
                *reinterpret_cast<uint2*>((u16*)out + base) = make_uint2(ou[0], ou[1]);
            }
        }
    }
}

// ---------------------------------------------------------------------------
extern "C" void kernel_launch(void* const* d_in, const int* in_sizes, int n_in,
                              void* d_out, int out_size, void* d_ws, size_t ws_size,
                              hipStream_t stream)
{
    const void* x     = d_in[0];
    const void* Wq    = d_in[1];
    const void* bq    = d_in[2];
    const void* Wk    = d_in[3];
    const void* bk    = d_in[4];
    const void* Wv    = d_in[5];
    const void* bv    = d_in[6];
    const void* gamma = d_in[7];
    const void* off   = d_in[8];

    char* ws = (char*)d_ws;
    size_t o = 0;
    auto alloc = [&](size_t bytes) { size_t r = o; o += (bytes + 255) & ~(size_t)255; return r; };
    int*   flag = (int*)(ws + alloc(256));
    float* dX   = (float*)(ws + alloc(129*2*4));
    float* dY   = (float*)(ws + alloc(129*2*4));
    u16*   pqk  = (u16*)(ws + alloc((size_t)4*16384*64*2));     // [B][HW][64]
    u16*   pvx  = (u16*)(ws + alloc((size_t)4*16384*256*2));    // [B][HW][256]
    u16*   pkc  = (u16*)(ws + alloc((size_t)4*128*128*32*2));   // [B][W][H][32]
    u16*   pvc  = (u16*)(ws + alloc((size_t)4*128*128*256*2));  // [B][W][H][256]
    u16*   qdH  = (u16*)(ws + alloc((size_t)16384*32*2));
    u16*   qdW  = (u16*)(ws + alloc((size_t)16384*32*2));
    u16*   kdW  = (u16*)(ws + alloc((size_t)16384*32*2));
    u16*   vdW  = (u16*)(ws + alloc((size_t)16384*256*2));      // [H][W][256]
    u16*   attbH= (u16*)(ws + alloc((size_t)4*128*128*128*2));  // [B][H][W][128]
    u16*   attbW= (u16*)(ws + alloc((size_t)4*128*128*128*2));
    u16*   T    = (u16*)(ws + alloc((size_t)4*128*128*256*2));  // [B][W][Hout][C] bf16
    u16*   WH   = (u16*)(ws + alloc((size_t)320*256*2));        // weight hi bf16
    u16*   WLo  = (u16*)(ws + alloc((size_t)320*256*2));        // weight lo bf16
    float* bias = (float*)(ws + alloc(320*4));
    // aliases (all within the workspace; d_out is NEVER used as scratch):
    u16*   xb   = T;                       // xb dead after k_proj_mfma; T written by k_outcol
    float* SH   = (float*)T;               // SH [B][W][H][128] f32 == 33.5 MB == sizeof(T)
    float* SWa  = (float*)attbH;           // SW rows w<64  live inside attbH bytes (f32)
    float* SWb  = (float*)attbW;           // SW rows w>=64 live inside attbW bytes (f32)

    k_detect   <<<1, 256, 0, stream>>>(x, flag);
    k_setup    <<<1, 256, 0, stream>>>(off, dX, dY, d_out, flag);
    k_wconv    <<<320, 256, 0, stream>>>(Wq, Wk, Wv, bq, bk, bv, WH, WLo, bias, flag);
    k_xconv    <<<dim3(512, 2), 256, 0, stream>>>(x, xb, flag);
    k_proj_mfma<<<512, 256, 0, stream>>>(xb, WH, WLo, bias, pqk, pvx);
    k_transqk  <<<192, 256, 0, stream>>>(pqk, pkc);
    k_transv   <<<6144, 256, 0, stream>>>(pvx, pvc);
    k_sample   <<<32768, 320, 0, stream>>>(pqk, pvx, dX, dY, qdH, pkc, pvc, qdW, kdW, vdW);
    k_scores   <<<1024, 256, 0, stream>>>(pqk, pkc, qdH, qdW, kdW, SH, SWa, SWb);
    k_softmax  <<<512, 256, 0, stream>>>(SH, SWa, SWb, attbH, attbW);
    k_outcol   <<<dim3(512, 2), 256, 0, stream>>>(pvc, attbH, T);
    k_outrow   <<<dim3(512, 2), 256, 0, stream>>>(pvx, vdW, attbW, T, x, gamma, d_out, flag);
    (void)in_sizes; (void)n_in; (void)out_size; (void)ws_size;
}

// Round 13
// 464.938 us; speedup vs baseline: 1.0815x; 1.0815x over previous
//
#include <hip/hip_runtime.h>
#include <hip/hip_bf16.h>

typedef unsigned short u16;
typedef unsigned int   u32;
typedef short bf16x8 __attribute__((ext_vector_type(8)));
typedef float f32x4  __attribute__((ext_vector_type(4)));

__device__ __forceinline__ float b2f(u16 u) {
    return __uint_as_float(((u32)u) << 16);
}
__device__ __forceinline__ u16 f2b(float f) {
    __hip_bfloat16 h = __float2bfloat16(f);
    u16 r; __builtin_memcpy(&r, &h, 2); return r;
}
// dtype-adaptive input load / output store (flag: 1 = fp32, 0 = bf16)
__device__ __forceinline__ float ldin(const void* p, size_t i, bool f32) {
    return f32 ? ((const float*)p)[i] : b2f(((const u16*)p)[i]);
}
__device__ __forceinline__ void stout(void* p, size_t i, float v, bool f32) {
    if (f32) ((float*)p)[i] = v; else ((u16*)p)[i] = f2b(v);
}

// ---------------------------------------------------------------------------
// K-1: dtype detector (fp32 low halves ~ uniform bits -> bf16-NaN patterns).
// ---------------------------------------------------------------------------
__global__ __launch_bounds__(256) void k_detect(const void* __restrict__ xraw, int* __restrict__ flag)
{
    const uint4* xv = (const uint4*)xraw;
    int t = threadIdx.x;
    int cnt = 0;
    for (int i = t; i < 8192; i += 256) {
        uint4 u = xv[i];
        u32 uu[4] = {u.x, u.y, u.z, u.w};
        #pragma unroll
        for (int q = 0; q < 4; ++q) {
            u16 a = (u16)(uu[q] & 0xffff), b = (u16)(uu[q] >> 16);
            if ((a & 0x7F80u) == 0x7F80u && (a & 0x007Fu) != 0) cnt++;
            if ((b & 0x7F80u) == 0x7F80u && (b & 0x007Fu) != 0) cnt++;
        }
    }
    __shared__ int red[256];
    red[t] = cnt; __syncthreads();
    for (int st = 128; st > 0; st >>= 1) {
        if (t < st) red[t] += red[t + st];
        __syncthreads();
    }
    if (t == 0) flag[0] = (red[0] > 16) ? 1 : 0;
}

// ---------------------------------------------------------------------------
// K0: pooled offset lines (dX, dY) + regloss.  offsets [2][131][131]
// ---------------------------------------------------------------------------
__global__ __launch_bounds__(256) void k_setup(const void* __restrict__ off,
                                               float* __restrict__ dX, float* __restrict__ dY,
                                               void* __restrict__ out, const int* __restrict__ flag) {
    bool f32 = flag[0] != 0;
    int t = threadIdx.x;
    if (t < 129) {
        for (int ch = 0; ch < 2; ++ch) {
            float s1 = 0.f, s2 = 0.f;
            for (int i = 0; i < 3; ++i)
                for (int j = 0; j < 3; ++j) {
                    s1 += ldin(off, ch*17161 + (t+i)*131 + (64+j), f32);
                    s2 += ldin(off, ch*17161 + (64+i)*131 + (t+j), f32);
                }
            dX[t*2 + ch] = s1 * (1.0f/9.0f);
            dY[t*2 + ch] = s2 * (1.0f/9.0f);
        }
    }
    float s = 0.f;
    for (int idx = t; idx < 17161; idx += 256) {
        float d = ldin(off, idx, f32) - ldin(off, 17161 + idx, f32);
        s += d * d * (1.0f/17161.0f);
    }
    for (int idx = t; idx < 34060; idx += 256) {
        int ch = idx / 17030;
        int rem = idx - ch*17030;
        int r = rem / 131, c = rem - r*131;
        float a = ldin(off, ch*17161 + r*131 + c, f32);
        float b = ldin(off, ch*17161 + (r+1)*131 + c, f32);
        float d = a - b;
        s += d * d * (1.0f/34060.0f);
    }
    __shared__ float red[256];
    red[t] = s; __syncthreads();
    for (int st = 128; st > 0; st >>= 1) {
        if (t < st) red[t] += red[t + st];
        __syncthreads();
    }
    if (t == 0) {
        float v = red[0];
        if (!(v == v)) v = -299.f;
        stout(out, (size_t)16777216, v, f32);
    }
}

// ---------------------------------------------------------------------------
// K0b: weight conversion, ONCE.  W rows stacked [Wq(32) | Wk(32) | Wv(256)]
// -> WH/WLo bf16 [320][256], bias fp32 [320].
// ---------------------------------------------------------------------------
__global__ __launch_bounds__(256) void k_wconv(
    const void* __restrict__ Wq, const void* __restrict__ Wk, const void* __restrict__ Wv,
    const void* __restrict__ bq, const void* __restrict__ bk, const void* __restrict__ bv,
    u16* __restrict__ WH, u16* __restrict__ WLo, float* __restrict__ bias,
    const int* __restrict__ flag)
{
    bool f32 = flag[0] != 0;
    int idx = blockIdx.x * 256 + threadIdx.x;          // grid 320 -> 81920
    if (idx < 81920) {
        int row = idx >> 8;
        int col = idx & 255;
        const void* src; int r;
        if (row < 32)      { src = Wq; r = row; }
        else if (row < 64) { src = Wk; r = row - 32; }
        else               { src = Wv; r = row - 64; }
        float wv = ldin(src, (size_t)r*256 + col, f32);
        u16 hi = f2b(wv);
        WH [idx] = hi;
        WLo[idx] = f2b(wv - b2f(hi));
    }
    if (blockIdx.x == 0 && threadIdx.x < 320) {
        int row = threadIdx.x;
        const void* src; int r;
        if (row < 32)      { src = bq; r = row; }
        else if (row < 64) { src = bk; r = row - 32; }
        else               { src = bv; r = row - 64; }
        bias[row] = ldin(src, r, f32);
    }
}

// ---------------------------------------------------------------------------
// K0c: x transpose+convert, ONCE.  x [B][C][HW] (f32 or bf16)
// -> xb bf16 [B*HW][256] (pixel-major, channel-fast).
// ---------------------------------------------------------------------------
__global__ __launch_bounds__(256) void k_xconv(const void* __restrict__ xraw,
                                               u16* __restrict__ xb,
                                               const int* __restrict__ flag)
{
    bool f32 = flag[0] != 0;
    int t = threadIdx.x;
    int bidx = blockIdx.x;                   // 0..511
    int b  = bidx >> 7;
    int p0 = (bidx & 127) * 128;
    int p  = p0 + (t & 127);
    int ch0 = blockIdx.y * 128 + (t >> 7) * 64;
    size_t xbase = ((size_t)b * 256) * 16384 + p;      // + c*16384
    u16* dst = xb + ((size_t)(b*16384 + p)) * 256 + ch0;
    for (int oct = 0; oct < 8; ++oct) {
        u32 w[4];
        #pragma unroll
        for (int q = 0; q < 4; ++q) {
            int c = ch0 + oct*8 + q*2;
            u16 lo, hi;
            if (f32) {
                const float* xf = (const float*)xraw;
                lo = f2b(xf[xbase + (size_t)c*16384]);
                hi = f2b(xf[xbase + (size_t)(c+1)*16384]);
            } else {
                const u16* xu = (const u16*)xraw;
                lo = xu[xbase + (size_t)c*16384];
                hi = xu[xbase + (size_t)(c+1)*16384];
            }
            w[q] = (u32)lo | ((u32)hi << 16);
        }
        *reinterpret_cast<uint4*>(dst + oct*8) = make_uint4(w[0], w[1], w[2], w[3]);
    }
}

// ---------------------------------------------------------------------------
// K1: MFMA projections (R8 best-measured config).  GEMM W[320,256] x X.
// XCD-aware block mapping: the 5 ot-slices sharing one 128KB xb slice are
// placed 8 block-IDs apart -> same XCD -> one L2 fetch serves all 5.
// ---------------------------------------------------------------------------
__global__ __launch_bounds__(256, 2) void k_proj_mfma(
    const u16* __restrict__ xb,
    const u16* __restrict__ WH, const u16* __restrict__ WLo,
    const float* __restrict__ bias,
    u16* __restrict__ pqk, u16* __restrict__ pvx)
{
    int t = threadIdx.x;
    int bid = blockIdx.x;                // 0..1279
    int xcd = bid & 7;
    int s   = bid >> 3;                  // 0..159
    int ot  = s % 5;                     // output slice
    int gpg = (s / 5) * 8 + xcd;         // pixel group 0..255
    int gp = gpg * 256;                  // global pixel base (b*16384 + p0)
    int b  = gp >> 14;
    int p0 = gp & 16383;
    int o_base = ot * 64;

    int wid = t >> 6, lane = t & 63;
    int quad = lane >> 4, n = lane & 15;

    const u16* xr  = xb + ((size_t)(gp + wid*64 + n)) * 256 + quad*8;
    const u16* whp = WH  + ((size_t)(o_base + n)) * 256 + quad*8;
    const u16* wlp = WLo + ((size_t)(o_base + n)) * 256 + quad*8;

    // preload all B-fragments (this lane's full xb row slice)
    bf16x8 bf[8][4];
    #pragma unroll
    for (int kc = 0; kc < 8; ++kc)
        #pragma unroll
        for (int pt = 0; pt < 4; ++pt)
            bf[kc][pt] = *reinterpret_cast<const bf16x8*>(xr + (size_t)pt*16*256 + kc*32);

    f32x4 acc[4][4];
    #pragma unroll
    for (int i = 0; i < 4; ++i)
        #pragma unroll
        for (int j = 0; j < 4; ++j) acc[i][j] = (f32x4){0.f, 0.f, 0.f, 0.f};

    #pragma unroll
    for (int kc = 0; kc < 8; ++kc) {
        int c0 = kc * 32;
        #pragma unroll
        for (int ot2 = 0; ot2 < 4; ++ot2) {
            bf16x8 ah = *reinterpret_cast<const bf16x8*>(whp + (size_t)ot2*16*256 + c0);
            bf16x8 al = *reinterpret_cast<const bf16x8*>(wlp + (size_t)ot2*16*256 + c0);
            #pragma unroll
            for (int pt = 0; pt < 4; ++pt) {
                acc[ot2][pt] = __builtin_amdgcn_mfma_f32_16x16x32_bf16(ah, bf[kc][pt], acc[ot2][pt], 0, 0, 0);
                acc[ot2][pt] = __builtin_amdgcn_mfma_f32_16x16x32_bf16(al, bf[kc][pt], acc[ot2][pt], 0, 0, 0);
            }
        }
    }
    #pragma unroll
    for (int ot2 = 0; ot2 < 4; ++ot2) {
        int o_l = ot2*16 + quad*4;
        int og  = o_base + o_l;
        float b0 = bias[og], b1 = bias[og+1], b2 = bias[og+2], b3 = bias[og+3];
        #pragma unroll
        for (int pt = 0; pt < 4; ++pt) {
            f32x4 a = acc[ot2][pt];
            int px = p0 + wid*64 + pt*16 + n;
            u32 w0 = (u32)f2b(a[0] + b0) | ((u32)f2b(a[1] + b1) << 16);
            u32 w1 = (u32)f2b(a[2] + b2) | ((u32)f2b(a[3] + b3) << 16);
            u16* dst;
            if (ot == 0) dst = pqk + ((size_t)(b*16384 + px))*64  + o_l;
            else         dst = pvx + ((size_t)(b*16384 + px))*256 + (o_base - 64 + o_l);
            *reinterpret_cast<uint2*>(dst) = make_uint2(w0, w1);
        }
    }
}

// ---------------------------------------------------------------------------
// K2: deformed bilinear sampling for batch 0.
// ---------------------------------------------------------------------------
__global__ __launch_bounds__(320) void k_sample(
    const u16* __restrict__ pqk, const u16* __restrict__ pvx,
    const float* __restrict__ dX, const float* __restrict__ dY,
    u16* __restrict__ qdH, u16* __restrict__ pkc, u16* __restrict__ pvc,
    u16* __restrict__ qdW, u16* __restrict__ kdW, u16* __restrict__ vdW)
{
    int bid = blockIdx.x;
    int variant = bid >> 14;
    int pt = bid & 16383;
    int t = threadIdx.x;
    int w, h;
    float xn, yn;
    if (variant == 0) {
        w = pt >> 7; h = pt & 127;
        xn = (-1.0f + (float)w     * (2.0f/128.0f)) + dX[(h+1)*2 + 0];
        yn = (-1.0f + (float)(h+1) * (2.0f/128.0f)) + dX[(h+1)*2 + 1];
    } else {
        h = pt >> 7; w = pt & 127;
        xn = (-1.0f + (float)(w+1) * (2.0f/128.0f)) + dY[(w+1)*2 + 0];
        yn = (-1.0f + (float)h     * (2.0f/128.0f)) + dY[(w+1)*2 + 1];
    }
    float fx = (xn + 1.0f) * 0.5f * 127.0f;
    float fy = (yn + 1.0f) * 0.5f * 127.0f;
    float x0f = floorf(fx), y0f = floorf(fy);
    float wx = fx - x0f, wy = fy - y0f;

    float wt[4]; int xi[4], yi[4]; bool vd[4];
    {
        float xs[2]  = { x0f, x0f + 1.0f };
        float ys[2]  = { y0f, y0f + 1.0f };
        float wxs[2] = { 1.0f - wx, wx };
        float wys[2] = { 1.0f - wy, wy };
        #pragma unroll
        for (int jy = 0; jy < 2; ++jy)
            #pragma unroll
            for (int jx = 0; jx < 2; ++jx) {
                int k = jy*2 + jx;
                vd[k] = (xs[jx] >= 0.f) && (xs[jx] < 128.f) && (ys[jy] >= 0.f) && (ys[jy] < 128.f);
                wt[k] = wxs[jx] * wys[jy];
                xi[k] = (int)fminf(fmaxf(xs[jx], 0.f), 127.f);
                yi[k] = (int)fminf(fmaxf(ys[jy], 0.f), 127.f);
            }
    }
    float val = 0.f;
    if (t < 64) {
        #pragma unroll
        for (int k = 0; k < 4; ++k)
            if (vd[k]) val += wt[k] * b2f(pqk[(size_t)(yi[k]*128 + xi[k])*64 + t]);
        if (t < 32) {
            if (variant == 0) qdH[(size_t)pt*32 + t] = f2b(val);
            else              qdW[(size_t)pt*32 + t] = f2b(val);
        } else {
            int c = t - 32;
            if (variant == 0) pkc[(size_t)pt*32 + c] = f2b(val);
            else              kdW[(size_t)pt*32 + c] = f2b(val);
        }
    } else {
        int c = t - 64;
        #pragma unroll
        for (int k = 0; k < 4; ++k)
            if (vd[k]) val += wt[k] * b2f(pvx[(size_t)(yi[k]*128 + xi[k])*256 + c]);
        if (variant == 0) pvc[(size_t)pt*256 + c] = f2b(val);
        else              vdW[(size_t)pt*256 + c] = f2b(val);
    }
}

// ---------------------------------------------------------------------------
// K3a: raw attention scores via MFMA.  1024 blocks = kind(2) x b(4) x line(128).
// b>=1 kind-0 K operand read DIRECTLY from pqk at stride 8192 (k_transqk
// eliminated — same strided-fragment pattern the Q operand already uses).
// ---------------------------------------------------------------------------
__global__ __launch_bounds__(256) void k_scores(
    const u16* __restrict__ pqk, const u16* __restrict__ pkc,
    const u16* __restrict__ qdH, const u16* __restrict__ qdW, const u16* __restrict__ kdW,
    float* __restrict__ SH, float* __restrict__ SWa, float* __restrict__ SWb)
{
    int bid = blockIdx.x;
    int kind = bid >> 9;
    int b    = (bid >> 7) & 3;
    int line = bid & 127;
    int t = threadIdx.x;
    int wid = t >> 6, lane = t & 63;
    int n16 = lane & 15, quad = lane >> 4;

    const u16 *Qb, *Kb; int qstride, kstride;
    float* Sb = nullptr;
    float* s_lo = nullptr; float* s_hi = nullptr;
    if (kind == 0) {                 // column scores, line = w
        if (b == 0) { Qb = qdH + (size_t)line*4096;                 qstride = 32;
                      Kb = pkc + (size_t)line*4096;                 kstride = 32;   }
        else        { Qb = pqk + ((size_t)(b*16384 + line))*64;     qstride = 8192;
                      Kb = Qb + 32;                                 kstride = 8192; }
        Sb = SH + ((size_t)(b*128 + line))*16384;
    } else {                          // row scores, line = h
        if (b == 0) { Qb = qdW + (size_t)line*4096;                 qstride = 32;
                      Kb = kdW + (size_t)line*4096;                 kstride = 32; }
        else        { Qb = pqk + ((size_t)(b*16384 + line*128))*64; qstride = 64;
                      Kb = Qb + 32;                                 kstride = 64; }
        size_t base = (size_t)(b*128 + line)*8192;
        s_lo = SWa + base;            // rows 0..63
        s_hi = SWb + base;            // rows 64..127 (index m-64)
    }

    bf16x8 af[2];
    #pragma unroll
    for (int m2 = 0; m2 < 2; ++m2)
        af[m2] = *reinterpret_cast<const bf16x8*>(
            Qb + (size_t)(wid*32 + m2*16 + n16)*qstride + quad*8);

    #pragma unroll
    for (int nt = 0; nt < 8; ++nt) {
        bf16x8 bf = *reinterpret_cast<const bf16x8*>(
            Kb + (size_t)(nt*16 + n16)*kstride + quad*8);
        f32x4 a0 = (f32x4){0.f,0.f,0.f,0.f};
        f32x4 a1 = (f32x4){0.f,0.f,0.f,0.f};
        a0 = __builtin_amdgcn_mfma_f32_16x16x32_bf16(af[0], bf, a0, 0, 0, 0);
        a1 = __builtin_amdgcn_mfma_f32_16x16x32_bf16(af[1], bf, a1, 0, 0, 0);
        int j = nt*16 + n16;
        int m0 = wid*32 + quad*4;
        if (kind == 0) {
            #pragma unroll
            for (int r = 0; r < 4; ++r) {
                Sb[(size_t)(m0 + r)*128 + j]      = a0[r];
                Sb[(size_t)(m0 + 16 + r)*128 + j] = a1[r];
            }
        } else {
            #pragma unroll
            for (int r = 0; r < 4; ++r) {
                int mA = m0 + r, mB = m0 + 16 + r;
                float* pA = (mA < 64) ? (s_lo + (size_t)mA*128 + j)
                                      : (s_hi + (size_t)(mA - 64)*128 + j);
                float* pB = (mB < 64) ? (s_lo + (size_t)mB*128 + j)
                                      : (s_hi + (size_t)(mB - 64)*128 + j);
                *pA = a0[r];
                *pB = a1[r];
            }
        }
    }
}

// ---------------------------------------------------------------------------
// K3b: joint softmax, register-resident.  block (b,h), 256 thr = (kind, w).
// ---------------------------------------------------------------------------
__global__ __launch_bounds__(256) void k_softmax(
    const float* __restrict__ SH, const float* __restrict__ SWa, const float* __restrict__ SWb,
    u16* __restrict__ attbH, u16* __restrict__ attbW)
{
    int b = blockIdx.x >> 7, h = blockIdx.x & 127;
    int t = threadIdx.x;
    int kind = t >> 7, w = t & 127;
    __shared__ float mh[256], zh[256];
    __shared__ float Mw[128], Iw[128];

    const float* src;
    if (kind == 0) {
        src = SH + (((size_t)(b*128 + w))*128 + h)*128;
    } else {
        size_t base = (size_t)(b*128 + h)*8192;
        src = (w < 64) ? (SWa + base + (size_t)w*128)
                       : (SWb + base + (size_t)(w - 64)*128);
    }
    const float4* s4 = reinterpret_cast<const float4*>(src);

    float4 row[32];
    #pragma unroll
    for (int q = 0; q < 32; ++q) row[q] = s4[q];

    if (kind == 0) {
        #pragma unroll
        for (int q = 0; q < 32; ++q) {
            float4 v = row[q];
            if (q*4     == h) v.x = -INFINITY;
            if (q*4 + 1 == h) v.y = -INFINITY;
            if (q*4 + 2 == h) v.z = -INFINITY;
            if (q*4 + 3 == h) v.w = -INFINITY;
            row[q] = v;
        }
    }

    float m = -INFINITY;
    #pragma unroll
    for (int q = 0; q < 32; ++q) {
        float4 v = row[q];
        m = fmaxf(m, fmaxf(fmaxf(v.x, v.y), fmaxf(v.z, v.w)));
    }
    mh[t] = m;
    __syncthreads();
    if (t < 128) Mw[t] = fmaxf(mh[t], mh[128 + t]);
    __syncthreads();

    float M = Mw[w];
    float Z = 0.f;
    #pragma unroll
    for (int q = 0; q < 32; ++q) {
        float4 v = row[q];
        Z += __expf(v.x - M) + __expf(v.y - M) + __expf(v.z - M) + __expf(v.w - M);
    }
    zh[t] = Z;
    __syncthreads();
    if (t < 128) Iw[t] = 1.0f / (zh[t] + zh[128 + t]);
    __syncthreads();

    float I = Iw[w];
    u16* dst = (kind == 0)
        ? attbH + (((size_t)(b*128 + h))*128 + w)*128
        : attbW + (((size_t)(b*128 + h))*128 + w)*128;
    #pragma unroll
    for (int q = 0; q < 16; ++q) {
        float4 v0 = row[2*q], v1 = row[2*q + 1];
        u32 o0 = (u32)f2b(__expf(v0.x - M) * I) | ((u32)f2b(__expf(v0.y - M) * I) << 16);
        u32 o1 = (u32)f2b(__expf(v0.z - M) * I) | ((u32)f2b(__expf(v0.w - M) * I) << 16);
        u32 o2 = (u32)f2b(__expf(v1.x - M) * I) | ((u32)f2b(__expf(v1.y - M) * I) << 16);
        u32 o3 = (u32)f2b(__expf(v1.z - M) * I) | ((u32)f2b(__expf(v1.w - M) * I) << 16);
        *reinterpret_cast<uint4*>(dst + q*8) = make_uint4(o0, o1, o2, o3);
    }
}

// ---------------------------------------------------------------------------
// LDS V-transpose staging shared by K4/K5:
// vt[c][m] = pack(V[row 2m][c], V[row 2m+1][c]) as u32, LDS row stride 68 u32.
// vstride = u16 distance between consecutive V rows in global memory
// (256 for contiguous slabs, 32768 when reading pvx columns directly).
// ---------------------------------------------------------------------------
__device__ __forceinline__ void stage_vt(u32* vt, const u16* Vsrc, size_t vstride, int t)
{
    int j2 = t & 63;                 // row pair index
    int c8 = (t >> 6) * 8;           // col octet base
    const u16* r0 = Vsrc + (size_t)(2*j2)*vstride;
    const u16* r1 = r0 + vstride;
    #pragma unroll
    for (int i = 0; i < 4; ++i) {
        int c = i*32 + c8;
        uint4 a  = *reinterpret_cast<const uint4*>(r0 + c);
        uint4 bb = *reinterpret_cast<const uint4*>(r1 + c);
        u32 au[4] = {a.x, a.y, a.z, a.w};
        u32 bu[4] = {bb.x, bb.y, bb.z, bb.w};
        #pragma unroll
        for (int e = 0; e < 4; ++e) {
            vt[(c + 2*e    )*68 + j2] = (au[e] & 0xffffu) | (bu[e] << 16);
            vt[(c + 2*e + 1)*68 + j2] = (au[e] >> 16)     | (bu[e] & 0xffff0000u);
        }
    }
}

// ---------------------------------------------------------------------------
// K4: column aggregation via MFMA, V via LDS transpose.
// T[b][w][k][c] = sum_h att * V;  V from pvc slab (b=0, sampled) or DIRECTLY
// from pvx columns at stride 32768 (b>=1; k_transv eliminated).
// ---------------------------------------------------------------------------
__global__ __launch_bounds__(256, 2) void k_outcol(const u16* __restrict__ pvc,
    const u16* __restrict__ pvx, const u16* __restrict__ attbH, u16* __restrict__ T)
{
    int b = blockIdx.x >> 7, w = blockIdx.x & 127;
    int half = blockIdx.y;
    int t = threadIdx.x;
    int wid = t >> 6, lane = t & 63;
    int n16 = lane & 15, quad = lane >> 4;

    __shared__ u32 vt[128*68];

    const u16* Abase = attbH + ((size_t)b*128)*16384 + (size_t)w*128;
    bf16x8 af[2][4];
    #pragma unroll
    for (int m2 = 0; m2 < 2; ++m2)
        #pragma unroll
        for (int ks = 0; ks < 4; ++ks)
            af[m2][ks] = *reinterpret_cast<const bf16x8*>(
                Abase + (size_t)(wid*32 + m2*16 + n16)*16384 + ks*32 + quad*8);

    if (b == 0)
        stage_vt(vt, pvc + (size_t)w*128*256 + half*128, 256, t);
    else
        stage_vt(vt, pvx + ((size_t)(b*16384 + w))*256 + half*128, 32768, t);
    __syncthreads();

    f32x4 acc[2][8];
    #pragma unroll
    for (int m2 = 0; m2 < 2; ++m2)
        #pragma unroll
        for (int nt = 0; nt < 8; ++nt) acc[m2][nt] = (f32x4){0.f,0.f,0.f,0.f};

    #pragma unroll
    for (int nt = 0; nt < 8; ++nt) {
        int c = nt*16 + n16;
        #pragma unroll
        for (int ks = 0; ks < 4; ++ks) {
            bf16x8 bfv = *reinterpret_cast<const bf16x8*>(&vt[c*68 + ks*16 + quad*4]);
            acc[0][nt] = __builtin_amdgcn_mfma_f32_16x16x32_bf16(af[0][ks], bfv, acc[0][nt], 0, 0, 0);
            acc[1][nt] = __builtin_amdgcn_mfma_f32_16x16x32_bf16(af[1][ks], bfv, acc[1][nt], 0, 0, 0);
        }
    }

    u16* Tbase = T + (((size_t)(b*128 + w))*128)*256 + half*128;
    #pragma unroll
    for (int m2 = 0; m2 < 2; ++m2) {
        int k0 = wid*32 + m2*16 + quad*4;
        #pragma unroll
        for (int nt = 0; nt < 8; ++nt) {
            int c = nt*16 + n16;
            f32x4 a = acc[m2][nt];
            #pragma unroll
            for (int r = 0; r < 4; ++r)
                Tbase[(size_t)(k0 + r)*256 + c] = f2b(a[r]);
        }
    }
}

// ---------------------------------------------------------------------------
// K5: row aggregation via MFMA + epilogue, V via LDS transpose.
// ---------------------------------------------------------------------------
__global__ __launch_bounds__(256, 2) void k_outrow(const u16* __restrict__ pvx, const u16* __restrict__ vdW,
    const u16* __restrict__ attbW, const u16* __restrict__ T, const void* __restrict__ xraw,
    const void* __restrict__ gamma, void* __restrict__ out, const int* __restrict__ flag)
{
    bool f32 = flag[0] != 0;
    int b = blockIdx.x >> 7, h = blockIdx.x & 127;
    int half = blockIdx.y;
    int t = threadIdx.x;
    int wid = t >> 6, lane = t & 63;
    int n16 = lane & 15, quad = lane >> 4;

    __shared__ u32 vt[128*68];

    const u16* Abase = attbW + ((size_t)(b*128 + h))*16384;
    bf16x8 af[2][4];
    #pragma unroll
    for (int m2 = 0; m2 < 2; ++m2)
        #pragma unroll
        for (int ks = 0; ks < 4; ++ks)
            af[m2][ks] = *reinterpret_cast<const bf16x8*>(
                Abase + (size_t)(wid*32 + m2*16 + n16)*128 + ks*32 + quad*8);

    const u16* Vsrc = ((b == 0) ? (vdW + (size_t)h*128*256)
                                : (pvx + ((size_t)b*16384 + h*128)*256)) + half*128;
    stage_vt(vt, Vsrc, 256, t);
    __syncthreads();

    f32x4 acc[2][8];
    #pragma unroll
    for (int m2 = 0; m2 < 2; ++m2)
        #pragma unroll
        for (int nt = 0; nt < 8; ++nt) acc[m2][nt] = (f32x4){0.f,0.f,0.f,0.f};

    #pragma unroll
    for (int nt = 0; nt < 8; ++nt) {
        int c = nt*16 + n16;
        #pragma unroll
        for (int ks = 0; ks < 4; ++ks) {
            bf16x8 bfv = *reinterpret_cast<const bf16x8*>(&vt[c*68 + ks*16 + quad*4]);
            acc[0][nt] = __builtin_amdgcn_mfma_f32_16x16x32_bf16(af[0][ks], bfv, acc[0][nt], 0, 0, 0);
            acc[1][nt] = __builtin_amdgcn_mfma_f32_16x16x32_bf16(af[1][ks], bfv, acc[1][nt], 0, 0, 0);
        }
    }

    float gm = ldin(gamma, 0, f32);
    const u16* Tbase = T + ((size_t)(b*128))*128*256 + (size_t)h*256 + half*128;

    #pragma unroll
    for (int m2 = 0; m2 < 2; ++m2) {
        int k0 = wid*32 + m2*16 + quad*4;
        #pragma unroll
        for (int nt = 0; nt < 8; ++nt) {
            int c = nt*16 + n16;
            int cg = half*128 + c;
            f32x4 a = acc[m2][nt];
            float r[4];
            #pragma unroll
            for (int i = 0; i < 4; ++i) {
                float hst = b2f(Tbase[(size_t)(k0 + i)*32768 + c]);
                r[i] = gm * (hst + a[i]);
            }
            size_t base = ((size_t)(b*256 + cg)*128 + h)*128 + k0;
            if (f32) {
                float4 xx = *reinterpret_cast<const float4*>((const float*)xraw + base);
                float4 rr;
                rr.x = r[0] + xx.x; rr.y = r[1] + xx.y;
                rr.z = r[2] + xx.z; rr.w = r[3] + xx.w;
                if (!(rr.x == rr.x)) rr.x = -299.f;
                if (!(rr.y == rr.y)) rr.y = -299.f;
                if (!(rr.z == rr.z)) rr.z = -299.f;
                if (!(rr.w == rr.w)) rr.w = -299.f;
                *reinterpret_cast<float4*>((float*)out + base) = rr;
            } else {
                uint2 xx = *reinterpret_cast<const uint2*>((const u16*)xraw + base);
                u32 xu[2] = { xx.x, xx.y };
                u32 ou[2];
                #pragma unroll
                for (int p2 = 0; p2 < 2; ++p2) {
                    float xlo = __uint_as_float(xu[p2] << 16);
                    float xhi = __uint_as_float(xu[p2] & 0xffff0000u);
                    float olo = r[p2*2]   + xlo;
                    float ohi = r[p2*2+1] + xhi;
                    if (!(olo == olo)) olo = -299.f;
                    if (!(ohi == ohi)) ohi = -299.f;
                    ou[p2] = (u32)f2b(olo) | ((u32)f2b(ohi) << 16);
                }
                *reinterpret_cast<uint2*>((u16*)out + base) = make_uint2(ou[0], ou[1]);
            }
        }
    }
}

// ---------------------------------------------------------------------------
extern "C" void kernel_launch(void* const* d_in, const int* in_sizes, int n_in,
                              void* d_out, int out_size, void* d_ws, size_t ws_size,
                              hipStream_t stream)
{
    const void* x     = d_in[0];
    const void* Wq    = d_in[1];
    const void* bq    = d_in[2];
    const void* Wk    = d_in[3];
    const void* bk    = d_in[4];
    const void* Wv    = d_in[5];
    const void* bv    = d_in[6];
    const void* gamma = d_in[7];
    const void* off   = d_in[8];

    char* ws = (char*)d_ws;
    size_t o = 0;
    auto alloc = [&](size_t bytes) { size_t r = o; o += (bytes + 255) & ~(size_t)255; return r; };
    int*   flag = (int*)(ws + alloc(256));
    float* dX   = (float*)(ws + alloc(129*2*4));
    float* dY   = (float*)(ws + alloc(129*2*4));
    u16*   pqk  = (u16*)(ws + alloc((size_t)4*16384*64*2));     // [B][HW][64]
    u16*   pvx  = (u16*)(ws + alloc((size_t)4*16384*256*2));    // [B][HW][256]
    u16*   pkc  = (u16*)(ws + alloc((size_t)16384*32*2));       // b=0 deformed K slab only
    u16*   pvc  = (u16*)(ws + alloc((size_t)16384*256*2));      // b=0 deformed V slab only
    u16*   qdH  = (u16*)(ws + alloc((size_t)16384*32*2));
    u16*   qdW  = (u16*)(ws + alloc((size_t)16384*32*2));
    u16*   kdW  = (u16*)(ws + alloc((size_t)16384*32*2));
    u16*   vdW  = (u16*)(ws + alloc((size_t)16384*256*2));      // [H][W][256]
    u16*   attbH= (u16*)(ws + alloc((size_t)4*128*128*128*2));  // [B][H][W][128]
    u16*   attbW= (u16*)(ws + alloc((size_t)4*128*128*128*2));
    u16*   T    = (u16*)(ws + alloc((size_t)4*128*128*256*2));  // [B][W][Hout][C] bf16
    u16*   WH   = (u16*)(ws + alloc((size_t)320*256*2));        // weight hi bf16
    u16*   WLo  = (u16*)(ws + alloc((size_t)320*256*2));        // weight lo bf16
    float* bias = (float*)(ws + alloc(320*4));
    // aliases (all within the workspace; d_out is NEVER used as scratch):
    u16*   xb   = T;                       // xb dead after k_proj_mfma; T written by k_outcol
    float* SH   = (float*)T;               // SH [B][W][H][128] f32 == 33.5 MB == sizeof(T)
    float* SWa  = (float*)attbH;           // SW rows w<64  live inside attbH bytes (f32)
    float* SWb  = (float*)attbW;           // SW rows w>=64 live inside attbW bytes (f32)

    k_detect   <<<1, 256, 0, stream>>>(x, flag);
    k_setup    <<<1, 256, 0, stream>>>(off, dX, dY, d_out, flag);
    k_wconv    <<<320, 256, 0, stream>>>(Wq, Wk, Wv, bq, bk, bv, WH, WLo, bias, flag);
    k_xconv    <<<dim3(512, 2), 256, 0, stream>>>(x, xb, flag);
    k_proj_mfma<<<1280, 256, 0, stream>>>(xb, WH, WLo, bias, pqk, pvx);
    k_sample   <<<32768, 320, 0, stream>>>(pqk, pvx, dX, dY, qdH, pkc, pvc, qdW, kdW, vdW);
    k_scores   <<<1024, 256, 0, stream>>>(pqk, pkc, qdH, qdW, kdW, SH, SWa, SWb);
    k_softmax  <<<512, 256, 0, stream>>>(SH, SWa, SWb, attbH, attbW);
    k_outcol   <<<dim3(512, 2), 256, 0, stream>>>(pvc, pvx, attbH, T);
    k_outrow   <<<dim3(512, 2), 256, 0, stream>>>(pvx, vdW, attbW, T, x, gamma, d_out, flag);
    (void)in_sizes; (void)n_in; (void)out_size; (void)ws_size;
}

// Round 14
// 427.974 us; speedup vs baseline: 1.1750x; 1.0864x over previous
//
#include <hip/hip_runtime.h>
#include <hip/hip_bf16.h>

typedef unsigned short u16;
typedef unsigned int   u32;
typedef short bf16x8 __attribute__((ext_vector_type(8)));
typedef float f32x4  __attribute__((ext_vector_type(4)));

__device__ __forceinline__ float b2f(u16 u) {
    return __uint_as_float(((u32)u) << 16);
}
__device__ __forceinline__ u16 f2b(float f) {
    __hip_bfloat16 h = __float2bfloat16(f);
    u16 r; __builtin_memcpy(&r, &h, 2); return r;
}
// dtype-adaptive input load / output store (flag: 1 = fp32, 0 = bf16)
__device__ __forceinline__ float ldin(const void* p, size_t i, bool f32) {
    return f32 ? ((const float*)p)[i] : b2f(((const u16*)p)[i]);
}
__device__ __forceinline__ void stout(void* p, size_t i, float v, bool f32) {
    if (f32) ((float*)p)[i] = v; else ((u16*)p)[i] = f2b(v);
}

// ---------------------------------------------------------------------------
// K-1: dtype detector (fp32 low halves ~ uniform bits -> bf16-NaN patterns).
// ---------------------------------------------------------------------------
__global__ __launch_bounds__(256) void k_detect(const void* __restrict__ xraw, int* __restrict__ flag)
{
    const uint4* xv = (const uint4*)xraw;
    int t = threadIdx.x;
    int cnt = 0;
    for (int i = t; i < 8192; i += 256) {
        uint4 u = xv[i];
        u32 uu[4] = {u.x, u.y, u.z, u.w};
        #pragma unroll
        for (int q = 0; q < 4; ++q) {
            u16 a = (u16)(uu[q] & 0xffff), b = (u16)(uu[q] >> 16);
            if ((a & 0x7F80u) == 0x7F80u && (a & 0x007Fu) != 0) cnt++;
            if ((b & 0x7F80u) == 0x7F80u && (b & 0x007Fu) != 0) cnt++;
        }
    }
    __shared__ int red[256];
    red[t] = cnt; __syncthreads();
    for (int st = 128; st > 0; st >>= 1) {
        if (t < st) red[t] += red[t + st];
        __syncthreads();
    }
    if (t == 0) flag[0] = (red[0] > 16) ? 1 : 0;
}

// ---------------------------------------------------------------------------
// K0: pooled offset lines (dX, dY) + regloss.  offsets [2][131][131]
// ---------------------------------------------------------------------------
__global__ __launch_bounds__(256) void k_setup(const void* __restrict__ off,
                                               float* __restrict__ dX, float* __restrict__ dY,
                                               void* __restrict__ out, const int* __restrict__ flag) {
    bool f32 = flag[0] != 0;
    int t = threadIdx.x;
    if (t < 129) {
        for (int ch = 0; ch < 2; ++ch) {
            float s1 = 0.f, s2 = 0.f;
            for (int i = 0; i < 3; ++i)
                for (int j = 0; j < 3; ++j) {
                    s1 += ldin(off, ch*17161 + (t+i)*131 + (64+j), f32);
                    s2 += ldin(off, ch*17161 + (64+i)*131 + (t+j), f32);
                }
            dX[t*2 + ch] = s1 * (1.0f/9.0f);
            dY[t*2 + ch] = s2 * (1.0f/9.0f);
        }
    }
    float s = 0.f;
    for (int idx = t; idx < 17161; idx += 256) {
        float d = ldin(off, idx, f32) - ldin(off, 17161 + idx, f32);
        s += d * d * (1.0f/17161.0f);
    }
    for (int idx = t; idx < 34060; idx += 256) {
        int ch = idx / 17030;
        int rem = idx - ch*17030;
        int r = rem / 131, c = rem - r*131;
        float a = ldin(off, ch*17161 + r*131 + c, f32);
        float b = ldin(off, ch*17161 + (r+1)*131 + c, f32);
        float d = a - b;
        s += d * d * (1.0f/34060.0f);
    }
    __shared__ float red[256];
    red[t] = s; __syncthreads();
    for (int st = 128; st > 0; st >>= 1) {
        if (t < st) red[t] += red[t + st];
        __syncthreads();
    }
    if (t == 0) {
        float v = red[0];
        if (!(v == v)) v = -299.f;
        stout(out, (size_t)16777216, v, f32);
    }
}

// ---------------------------------------------------------------------------
// K0b: weight conversion, ONCE.  W rows stacked [Wq(32) | Wk(32) | Wv(256)]
// -> WH/WLo bf16 [320][256], bias fp32 [320].
// ---------------------------------------------------------------------------
__global__ __launch_bounds__(256) void k_wconv(
    const void* __restrict__ Wq, const void* __restrict__ Wk, const void* __restrict__ Wv,
    const void* __restrict__ bq, const void* __restrict__ bk, const void* __restrict__ bv,
    u16* __restrict__ WH, u16* __restrict__ WLo, float* __restrict__ bias,
    const int* __restrict__ flag)
{
    bool f32 = flag[0] != 0;
    int idx = blockIdx.x * 256 + threadIdx.x;          // grid 320 -> 81920
    if (idx < 81920) {
        int row = idx >> 8;
        int col = idx & 255;
        const void* src; int r;
        if (row < 32)      { src = Wq; r = row; }
        else if (row < 64) { src = Wk; r = row - 32; }
        else               { src = Wv; r = row - 64; }
        float wv = ldin(src, (size_t)r*256 + col, f32);
        u16 hi = f2b(wv);
        WH [idx] = hi;
        WLo[idx] = f2b(wv - b2f(hi));
    }
    if (blockIdx.x == 0 && threadIdx.x < 320) {
        int row = threadIdx.x;
        const void* src; int r;
        if (row < 32)      { src = bq; r = row; }
        else if (row < 64) { src = bk; r = row - 32; }
        else               { src = bv; r = row - 64; }
        bias[row] = ldin(src, r, f32);
    }
}

// ---------------------------------------------------------------------------
// K0c: x transpose+convert via LDS tile, ONCE.  x [B][C][HW] -> xb [B*HW][256].
// Block = 64 pixels x 256 channels.  Read: coalesced 256B p-rows.  LDS tile
// lt[p][cpair] u32, row stride 131 (odd -> p-strided writes conflict-free).
// Write: wave writes two FULL 512B xb rows per pass (1KB contiguous) ->
// full-line merge; kills the 2.4x write amplification R13 measured (79MB).
// ---------------------------------------------------------------------------
__global__ __launch_bounds__(256) void k_xconv(const void* __restrict__ xraw,
                                               u16* __restrict__ xb,
                                               const int* __restrict__ flag)
{
    bool f32 = flag[0] != 0;
    int t = threadIdx.x;
    int gp = blockIdx.x * 64;            // global pixel base
    int b  = gp >> 14;
    int p0 = gp & 16383;

    __shared__ u32 lt[64*131];

    int p  = t & 63;
    int co = t >> 6;                     // 0..3
    size_t xbase = ((size_t)b*256)*16384 + p0 + p;
    #pragma unroll
    for (int i = 0; i < 32; ++i) {
        int cp = i*4 + co;               // channel pair 0..127
        u16 lo, hi;
        if (f32) {
            const float* xf = (const float*)xraw;
            lo = f2b(xf[xbase + (size_t)(2*cp)*16384]);
            hi = f2b(xf[xbase + (size_t)(2*cp+1)*16384]);
        } else {
            const u16* xu = (const u16*)xraw;
            lo = xu[xbase + (size_t)(2*cp)*16384];
            hi = xu[xbase + (size_t)(2*cp+1)*16384];
        }
        lt[p*131 + cp] = (u32)lo | ((u32)hi << 16);
    }
    __syncthreads();
    int u4 = t & 31;                     // uint4 index within 512B row
    int pr = t >> 5;                     // 0..7
    #pragma unroll
    for (int pass = 0; pass < 8; ++pass) {
        int pp = pass*8 + pr;
        u32 w0 = lt[pp*131 + u4*4 + 0];
        u32 w1 = lt[pp*131 + u4*4 + 1];
        u32 w2 = lt[pp*131 + u4*4 + 2];
        u32 w3 = lt[pp*131 + u4*4 + 3];
        *reinterpret_cast<uint4*>(xb + ((size_t)(gp + pp))*256 + u4*8) =
            make_uint4(w0, w1, w2, w3);
    }
}

// ---------------------------------------------------------------------------
// K1: MFMA projections (R8 best-measured config).  GEMM W[320,256] x X.
// XCD-aware block mapping: the 5 ot-slices sharing one 128KB xb slice are
// placed 8 block-IDs apart -> same XCD -> one L2 fetch serves all 5.
// ---------------------------------------------------------------------------
__global__ __launch_bounds__(256, 2) void k_proj_mfma(
    const u16* __restrict__ xb,
    const u16* __restrict__ WH, const u16* __restrict__ WLo,
    const float* __restrict__ bias,
    u16* __restrict__ pqk, u16* __restrict__ pvx)
{
    int t = threadIdx.x;
    int bid = blockIdx.x;                // 0..1279
    int xcd = bid & 7;
    int s   = bid >> 3;                  // 0..159
    int ot  = s % 5;                     // output slice
    int gpg = (s / 5) * 8 + xcd;         // pixel group 0..255
    int gp = gpg * 256;                  // global pixel base (b*16384 + p0)
    int b  = gp >> 14;
    int p0 = gp & 16383;
    int o_base = ot * 64;

    int wid = t >> 6, lane = t & 63;
    int quad = lane >> 4, n = lane & 15;

    const u16* xr  = xb + ((size_t)(gp + wid*64 + n)) * 256 + quad*8;
    const u16* whp = WH  + ((size_t)(o_base + n)) * 256 + quad*8;
    const u16* wlp = WLo + ((size_t)(o_base + n)) * 256 + quad*8;

    // preload all B-fragments (this lane's full xb row slice)
    bf16x8 bf[8][4];
    #pragma unroll
    for (int kc = 0; kc < 8; ++kc)
        #pragma unroll
        for (int pt = 0; pt < 4; ++pt)
            bf[kc][pt] = *reinterpret_cast<const bf16x8*>(xr + (size_t)pt*16*256 + kc*32);

    f32x4 acc[4][4];
    #pragma unroll
    for (int i = 0; i < 4; ++i)
        #pragma unroll
        for (int j = 0; j < 4; ++j) acc[i][j] = (f32x4){0.f, 0.f, 0.f, 0.f};

    #pragma unroll
    for (int kc = 0; kc < 8; ++kc) {
        int c0 = kc * 32;
        #pragma unroll
        for (int ot2 = 0; ot2 < 4; ++ot2) {
            bf16x8 ah = *reinterpret_cast<const bf16x8*>(whp + (size_t)ot2*16*256 + c0);
            bf16x8 al = *reinterpret_cast<const bf16x8*>(wlp + (size_t)ot2*16*256 + c0);
            #pragma unroll
            for (int pt = 0; pt < 4; ++pt) {
                acc[ot2][pt] = __builtin_amdgcn_mfma_f32_16x16x32_bf16(ah, bf[kc][pt], acc[ot2][pt], 0, 0, 0);
                acc[ot2][pt] = __builtin_amdgcn_mfma_f32_16x16x32_bf16(al, bf[kc][pt], acc[ot2][pt], 0, 0, 0);
            }
        }
    }
    #pragma unroll
    for (int ot2 = 0; ot2 < 4; ++ot2) {
        int o_l = ot2*16 + quad*4;
        int og  = o_base + o_l;
        float b0 = bias[og], b1 = bias[og+1], b2 = bias[og+2], b3 = bias[og+3];
        #pragma unroll
        for (int pt = 0; pt < 4; ++pt) {
            f32x4 a = acc[ot2][pt];
            int px = p0 + wid*64 + pt*16 + n;
            u32 w0 = (u32)f2b(a[0] + b0) | ((u32)f2b(a[1] + b1) << 16);
            u32 w1 = (u32)f2b(a[2] + b2) | ((u32)f2b(a[3] + b3) << 16);
            u16* dst;
            if (ot == 0) dst = pqk + ((size_t)(b*16384 + px))*64  + o_l;
            else         dst = pvx + ((size_t)(b*16384 + px))*256 + (o_base - 64 + o_l);
            *reinterpret_cast<uint2*>(dst) = make_uint2(w0, w1);
        }
    }
}

// ---------------------------------------------------------------------------
// K2: deformed bilinear sampling for batch 0.
// ---------------------------------------------------------------------------
__global__ __launch_bounds__(320) void k_sample(
    const u16* __restrict__ pqk, const u16* __restrict__ pvx,
    const float* __restrict__ dX, const float* __restrict__ dY,
    u16* __restrict__ qdH, u16* __restrict__ pkc, u16* __restrict__ pvc,
    u16* __restrict__ qdW, u16* __restrict__ kdW, u16* __restrict__ vdW)
{
    int bid = blockIdx.x;
    int variant = bid >> 14;
    int pt = bid & 16383;
    int t = threadIdx.x;
    int w, h;
    float xn, yn;
    if (variant == 0) {
        w = pt >> 7; h = pt & 127;
        xn = (-1.0f + (float)w     * (2.0f/128.0f)) + dX[(h+1)*2 + 0];
        yn = (-1.0f + (float)(h+1) * (2.0f/128.0f)) + dX[(h+1)*2 + 1];
    } else {
        h = pt >> 7; w = pt & 127;
        xn = (-1.0f + (float)(w+1) * (2.0f/128.0f)) + dY[(w+1)*2 + 0];
        yn = (-1.0f + (float)h     * (2.0f/128.0f)) + dY[(w+1)*2 + 1];
    }
    float fx = (xn + 1.0f) * 0.5f * 127.0f;
    float fy = (yn + 1.0f) * 0.5f * 127.0f;
    float x0f = floorf(fx), y0f = floorf(fy);
    float wx = fx - x0f, wy = fy - y0f;

    float wt[4]; int xi[4], yi[4]; bool vd[4];
    {
        float xs[2]  = { x0f, x0f + 1.0f };
        float ys[2]  = { y0f, y0f + 1.0f };
        float wxs[2] = { 1.0f - wx, wx };
        float wys[2] = { 1.0f - wy, wy };
        #pragma unroll
        for (int jy = 0; jy < 2; ++jy)
            #pragma unroll
            for (int jx = 0; jx < 2; ++jx) {
                int k = jy*2 + jx;
                vd[k] = (xs[jx] >= 0.f) && (xs[jx] < 128.f) && (ys[jy] >= 0.f) && (ys[jy] < 128.f);
                wt[k] = wxs[jx] * wys[jy];
                xi[k] = (int)fminf(fmaxf(xs[jx], 0.f), 127.f);
                yi[k] = (int)fminf(fmaxf(ys[jy], 0.f), 127.f);
            }
    }
    float val = 0.f;
    if (t < 64) {
        #pragma unroll
        for (int k = 0; k < 4; ++k)
            if (vd[k]) val += wt[k] * b2f(pqk[(size_t)(yi[k]*128 + xi[k])*64 + t]);
        if (t < 32) {
            if (variant == 0) qdH[(size_t)pt*32 + t] = f2b(val);
            else              qdW[(size_t)pt*32 + t] = f2b(val);
        } else {
            int c = t - 32;
            if (variant == 0) pkc[(size_t)pt*32 + c] = f2b(val);
            else              kdW[(size_t)pt*32 + c] = f2b(val);
        }
    } else {
        int c = t - 64;
        #pragma unroll
        for (int k = 0; k < 4; ++k)
            if (vd[k]) val += wt[k] * b2f(pvx[(size_t)(yi[k]*128 + xi[k])*256 + c]);
        if (variant == 0) pvc[(size_t)pt*256 + c] = f2b(val);
        else              vdW[(size_t)pt*256 + c] = f2b(val);
    }
}

// ---------------------------------------------------------------------------
// K3a: raw attention scores via MFMA.  1024 blocks = kind(2) x b(4) x line(128).
// ---------------------------------------------------------------------------
__global__ __launch_bounds__(256) void k_scores(
    const u16* __restrict__ pqk, const u16* __restrict__ pkc,
    const u16* __restrict__ qdH, const u16* __restrict__ qdW, const u16* __restrict__ kdW,
    float* __restrict__ SH, float* __restrict__ SWa, float* __restrict__ SWb)
{
    int bid = blockIdx.x;
    int kind = bid >> 9;
    int b    = (bid >> 7) & 3;
    int line = bid & 127;
    int t = threadIdx.x;
    int wid = t >> 6, lane = t & 63;
    int n16 = lane & 15, quad = lane >> 4;

    const u16 *Qb, *Kb; int qstride, kstride;
    float* Sb = nullptr;
    float* s_lo = nullptr; float* s_hi = nullptr;
    if (kind == 0) {                 // column scores, line = w
        if (b == 0) { Qb = qdH + (size_t)line*4096;                 qstride = 32;
                      Kb = pkc + (size_t)line*4096;                 kstride = 32;   }
        else        { Qb = pqk + ((size_t)(b*16384 + line))*64;     qstride = 8192;
                      Kb = Qb + 32;                                 kstride = 8192; }
        Sb = SH + ((size_t)(b*128 + line))*16384;
    } else {                          // row scores, line = h
        if (b == 0) { Qb = qdW + (size_t)line*4096;                 qstride = 32;
                      Kb = kdW + (size_t)line*4096;                 kstride = 32; }
        else        { Qb = pqk + ((size_t)(b*16384 + line*128))*64; qstride = 64;
                      Kb = Qb + 32;                                 kstride = 64; }
        size_t base = (size_t)(b*128 + line)*8192;
        s_lo = SWa + base;            // rows 0..63
        s_hi = SWb + base;            // rows 64..127 (index m-64)
    }

    bf16x8 af[2];
    #pragma unroll
    for (int m2 = 0; m2 < 2; ++m2)
        af[m2] = *reinterpret_cast<const bf16x8*>(
            Qb + (size_t)(wid*32 + m2*16 + n16)*qstride + quad*8);

    #pragma unroll
    for (int nt = 0; nt < 8; ++nt) {
        bf16x8 bf = *reinterpret_cast<const bf16x8*>(
            Kb + (size_t)(nt*16 + n16)*kstride + quad*8);
        f32x4 a0 = (f32x4){0.f,0.f,0.f,0.f};
        f32x4 a1 = (f32x4){0.f,0.f,0.f,0.f};
        a0 = __builtin_amdgcn_mfma_f32_16x16x32_bf16(af[0], bf, a0, 0, 0, 0);
        a1 = __builtin_amdgcn_mfma_f32_16x16x32_bf16(af[1], bf, a1, 0, 0, 0);
        int j = nt*16 + n16;
        int m0 = wid*32 + quad*4;
        if (kind == 0) {
            #pragma unroll
            for (int r = 0; r < 4; ++r) {
                Sb[(size_t)(m0 + r)*128 + j]      = a0[r];
                Sb[(size_t)(m0 + 16 + r)*128 + j] = a1[r];
            }
        } else {
            #pragma unroll
            for (int r = 0; r < 4; ++r) {
                int mA = m0 + r, mB = m0 + 16 + r;
                float* pA = (mA < 64) ? (s_lo + (size_t)mA*128 + j)
                                      : (s_hi + (size_t)(mA - 64)*128 + j);
                float* pB = (mB < 64) ? (s_lo + (size_t)mB*128 + j)
                                      : (s_hi + (size_t)(mB - 64)*128 + j);
                *pA = a0[r];
                *pB = a1[r];
            }
        }
    }
}

// ---------------------------------------------------------------------------
// K3b: joint softmax, register-resident.  block (b,h), 256 thr = (kind, w).
// ---------------------------------------------------------------------------
__global__ __launch_bounds__(256) void k_softmax(
    const float* __restrict__ SH, const float* __restrict__ SWa, const float* __restrict__ SWb,
    u16* __restrict__ attbH, u16* __restrict__ attbW)
{
    int b = blockIdx.x >> 7, h = blockIdx.x & 127;
    int t = threadIdx.x;
    int kind = t >> 7, w = t & 127;
    __shared__ float mh[256], zh[256];
    __shared__ float Mw[128], Iw[128];

    const float* src;
    if (kind == 0) {
        src = SH + (((size_t)(b*128 + w))*128 + h)*128;
    } else {
        size_t base = (size_t)(b*128 + h)*8192;
        src = (w < 64) ? (SWa + base + (size_t)w*128)
                       : (SWb + base + (size_t)(w - 64)*128);
    }
    const float4* s4 = reinterpret_cast<const float4*>(src);

    float4 row[32];
    #pragma unroll
    for (int q = 0; q < 32; ++q) row[q] = s4[q];

    if (kind == 0) {
        #pragma unroll
        for (int q = 0; q < 32; ++q) {
            float4 v = row[q];
            if (q*4     == h) v.x = -INFINITY;
            if (q*4 + 1 == h) v.y = -INFINITY;
            if (q*4 + 2 == h) v.z = -INFINITY;
            if (q*4 + 3 == h) v.w = -INFINITY;
            row[q] = v;
        }
    }

    float m = -INFINITY;
    #pragma unroll
    for (int q = 0; q < 32; ++q) {
        float4 v = row[q];
        m = fmaxf(m, fmaxf(fmaxf(v.x, v.y), fmaxf(v.z, v.w)));
    }
    mh[t] = m;
    __syncthreads();
    if (t < 128) Mw[t] = fmaxf(mh[t], mh[128 + t]);
    __syncthreads();

    float M = Mw[w];
    float Z = 0.f;
    #pragma unroll
    for (int q = 0; q < 32; ++q) {
        float4 v = row[q];
        Z += __expf(v.x - M) + __expf(v.y - M) + __expf(v.z - M) + __expf(v.w - M);
    }
    zh[t] = Z;
    __syncthreads();
    if (t < 128) Iw[t] = 1.0f / (zh[t] + zh[128 + t]);
    __syncthreads();

    float I = Iw[w];
    u16* dst = (kind == 0)
        ? attbH + (((size_t)(b*128 + h))*128 + w)*128
        : attbW + (((size_t)(b*128 + h))*128 + w)*128;
    #pragma unroll
    for (int q = 0; q < 16; ++q) {
        float4 v0 = row[2*q], v1 = row[2*q + 1];
        u32 o0 = (u32)f2b(__expf(v0.x - M) * I) | ((u32)f2b(__expf(v0.y - M) * I) << 16);
        u32 o1 = (u32)f2b(__expf(v0.z - M) * I) | ((u32)f2b(__expf(v0.w - M) * I) << 16);
        u32 o2 = (u32)f2b(__expf(v1.x - M) * I) | ((u32)f2b(__expf(v1.y - M) * I) << 16);
        u32 o3 = (u32)f2b(__expf(v1.z - M) * I) | ((u32)f2b(__expf(v1.w - M) * I) << 16);
        *reinterpret_cast<uint4*>(dst + q*8) = make_uint4(o0, o1, o2, o3);
    }
}

// ---------------------------------------------------------------------------
// LDS V-transpose staging shared by K4/K5:
// vt[c][m] = pack(V[row 2m][c], V[row 2m+1][c]) as u32, LDS row stride 68 u32.
// vstride = u16 distance between consecutive V rows in global memory.
// ---------------------------------------------------------------------------
__device__ __forceinline__ void stage_vt(u32* vt, const u16* Vsrc, size_t vstride, int t)
{
    int j2 = t & 63;                 // row pair index
    int c8 = (t >> 6) * 8;           // col octet base
    const u16* r0 = Vsrc + (size_t)(2*j2)*vstride;
    const u16* r1 = r0 + vstride;
    #pragma unroll
    for (int i = 0; i < 4; ++i) {
        int c = i*32 + c8;
        uint4 a  = *reinterpret_cast<const uint4*>(r0 + c);
        uint4 bb = *reinterpret_cast<const uint4*>(r1 + c);
        u32 au[4] = {a.x, a.y, a.z, a.w};
        u32 bu[4] = {bb.x, bb.y, bb.z, bb.w};
        #pragma unroll
        for (int e = 0; e < 4; ++e) {
            vt[(c + 2*e    )*68 + j2] = (au[e] & 0xffffu) | (bu[e] << 16);
            vt[(c + 2*e + 1)*68 + j2] = (au[e] >> 16)     | (bu[e] & 0xffff0000u);
        }
    }
}

// ---------------------------------------------------------------------------
// K4: column aggregation via MFMA, V via LDS transpose.
// T[b][w][k][c] = sum_h att * V;  V from pvc slab (b=0) or pvx columns (b>=1).
// ---------------------------------------------------------------------------
__global__ __launch_bounds__(256, 2) void k_outcol(const u16* __restrict__ pvc,
    const u16* __restrict__ pvx, const u16* __restrict__ attbH, u16* __restrict__ T)
{
    int b = blockIdx.x >> 7, w = blockIdx.x & 127;
    int half = blockIdx.y;
    int t = threadIdx.x;
    int wid = t >> 6, lane = t & 63;
    int n16 = lane & 15, quad = lane >> 4;

    __shared__ u32 vt[128*68];

    const u16* Abase = attbH + ((size_t)b*128)*16384 + (size_t)w*128;
    bf16x8 af[2][4];
    #pragma unroll
    for (int m2 = 0; m2 < 2; ++m2)
        #pragma unroll
        for (int ks = 0; ks < 4; ++ks)
            af[m2][ks] = *reinterpret_cast<const bf16x8*>(
                Abase + (size_t)(wid*32 + m2*16 + n16)*16384 + ks*32 + quad*8);

    if (b == 0)
        stage_vt(vt, pvc + (size_t)w*128*256 + half*128, 256, t);
    else
        stage_vt(vt, pvx + ((size_t)(b*16384 + w))*256 + half*128, 32768, t);
    __syncthreads();

    f32x4 acc[2][8];
    #pragma unroll
    for (int m2 = 0; m2 < 2; ++m2)
        #pragma unroll
        for (int nt = 0; nt < 8; ++nt) acc[m2][nt] = (f32x4){0.f,0.f,0.f,0.f};

    #pragma unroll
    for (int nt = 0; nt < 8; ++nt) {
        int c = nt*16 + n16;
        #pragma unroll
        for (int ks = 0; ks < 4; ++ks) {
            bf16x8 bfv = *reinterpret_cast<const bf16x8*>(&vt[c*68 + ks*16 + quad*4]);
            acc[0][nt] = __builtin_amdgcn_mfma_f32_16x16x32_bf16(af[0][ks], bfv, acc[0][nt], 0, 0, 0);
            acc[1][nt] = __builtin_amdgcn_mfma_f32_16x16x32_bf16(af[1][ks], bfv, acc[1][nt], 0, 0, 0);
        }
    }

    u16* Tbase = T + (((size_t)(b*128 + w))*128)*256 + half*128;
    #pragma unroll
    for (int m2 = 0; m2 < 2; ++m2) {
        int k0 = wid*32 + m2*16 + quad*4;
        #pragma unroll
        for (int nt = 0; nt < 8; ++nt) {
            int c = nt*16 + n16;
            f32x4 a = acc[m2][nt];
            #pragma unroll
            for (int r = 0; r < 4; ++r)
                Tbase[(size_t)(k0 + r)*256 + c] = f2b(a[r]);
        }
    }
}

// ---------------------------------------------------------------------------
// K5: row aggregation via MFMA + epilogue, V via LDS transpose.
// ---------------------------------------------------------------------------
__global__ __launch_bounds__(256, 2) void k_outrow(const u16* __restrict__ pvx, const u16* __restrict__ vdW,
    const u16* __restrict__ attbW, const u16* __restrict__ T, const void* __restrict__ xraw,
    const void* __restrict__ gamma, void* __restrict__ out, const int* __restrict__ flag)
{
    bool f32 = flag[0] != 0;
    int b = blockIdx.x >> 7, h = blockIdx.x & 127;
    int half = blockIdx.y;
    int t = threadIdx.x;
    int wid = t >> 6, lane = t & 63;
    int n16 = lane & 15, quad = lane >> 4;

    __shared__ u32 vt[128*68];

    const u16* Abase = attbW + ((size_t)(b*128 + h))*16384;
    bf16x8 af[2][4];
    #pragma unroll
    for (int m2 = 0; m2 < 2; ++m2)
        #pragma unroll
        for (int ks = 0; ks < 4; ++ks)
            af[m2][ks] = *reinterpret_cast<const bf16x8*>(
                Abase + (size_t)(wid*32 + m2*16 + n16)*128 + ks*32 + quad*8);

    const u16* Vsrc = ((b == 0) ? (vdW + (size_t)h*128*256)
                                : (pvx + ((size_t)b*16384 + h*128)*256)) + half*128;
    stage_vt(vt, Vsrc, 256, t);
    __syncthreads();

    f32x4 acc[2][8];
    #pragma unroll
    for (int m2 = 0; m2 < 2; ++m2)
        #pragma unroll
        for (int nt = 0; nt < 8; ++nt) acc[m2][nt] = (f32x4){0.f,0.f,0.f,0.f};

    #pragma unroll
    for (int nt = 0; nt < 8; ++nt) {
        int c = nt*16 + n16;
        #pragma unroll
        for (int ks = 0; ks < 4; ++ks) {
            bf16x8 bfv = *reinterpret_cast<const bf16x8*>(&vt[c*68 + ks*16 + quad*4]);
            acc[0][nt] = __builtin_amdgcn_mfma_f32_16x16x32_bf16(af[0][ks], bfv, acc[0][nt], 0, 0, 0);
            acc[1][nt] = __builtin_amdgcn_mfma_f32_16x16x32_bf16(af[1][ks], bfv, acc[1][nt], 0, 0, 0);
        }
    }

    float gm = ldin(gamma, 0, f32);
    const u16* Tbase = T + ((size_t)(b*128))*128*256 + (size_t)h*256 + half*128;

    #pragma unroll
    for (int m2 = 0; m2 < 2; ++m2) {
        int k0 = wid*32 + m2*16 + quad*4;
        #pragma unroll
        for (int nt = 0; nt < 8; ++nt) {
            int c = nt*16 + n16;
            int cg = half*128 + c;
            f32x4 a = acc[m2][nt];
            float r[4];
            #pragma unroll
            for (int i = 0; i < 4; ++i) {
                float hst = b2f(Tbase[(size_t)(k0 + i)*32768 + c]);
                r[i] = gm * (hst + a[i]);
            }
            size_t base = ((size_t)(b*256 + cg)*128 + h)*128 + k0;
            if (f32) {
                float4 xx = *reinterpret_cast<const float4*>((const float*)xraw + base);
                float4 rr;
                rr.x = r[0] + xx.x; rr.y = r[1] + xx.y;
                rr.z = r[2] + xx.z; rr.w = r[3] + xx.w;
                if (!(rr.x == rr.x)) rr.x = -299.f;
                if (!(rr.y == rr.y)) rr.y = -299.f;
                if (!(rr.z == rr.z)) rr.z = -299.f;
                if (!(rr.w == rr.w)) rr.w = -299.f;
                *reinterpret_cast<float4*>((float*)out + base) = rr;
            } else {
                uint2 xx = *reinterpret_cast<const uint2*>((const u16*)xraw + base);
                u32 xu[2] = { xx.x, xx.y };
                u32 ou[2];
                #pragma unroll
                for (int p2 = 0; p2 < 2; ++p2) {
                    float xlo = __uint_as_float(xu[p2] << 16);
                    float xhi = __uint_as_float(xu[p2] & 0xffff0000u);
                    float olo = r[p2*2]   + xlo;
                    float ohi = r[p2*2+1] + xhi;
                    if (!(olo == olo)) olo = -299.f;
                    if (!(ohi == ohi)) ohi = -299.f;
                    ou[p2] = (u32)f2b(olo) | ((u32)f2b(ohi) << 16);
                }
                *reinterpret_cast<uint2*>((u16*)out + base) = make_uint2(ou[0], ou[1]);
            }
        }
    }
}

// ---------------------------------------------------------------------------
extern "C" void kernel_launch(void* const* d_in, const int* in_sizes, int n_in,
                              void* d_out, int out_size, void* d_ws, size_t ws_size,
                              hipStream_t stream)
{
    const void* x     = d_in[0];
    const void* Wq    = d_in[1];
    const void* bq    = d_in[2];
    const void* Wk    = d_in[3];
    const void* bk    = d_in[4];
    const void* Wv    = d_in[5];
    const void* bv    = d_in[6];
    const void* gamma = d_in[7];
    const void* off   = d_in[8];

    char* ws = (char*)d_ws;
    size_t o = 0;
    auto alloc = [&](size_t bytes) { size_t r = o; o += (bytes + 255) & ~(size_t)255; return r; };
    int*   flag = (int*)(ws + alloc(256));
    float* dX   = (float*)(ws + alloc(129*2*4));
    float* dY   = (float*)(ws + alloc(129*2*4));
    u16*   pqk  = (u16*)(ws + alloc((size_t)4*16384*64*2));     // [B][HW][64]
    u16*   pvx  = (u16*)(ws + alloc((size_t)4*16384*256*2));    // [B][HW][256]
    u16*   pkc  = (u16*)(ws + alloc((size_t)16384*32*2));       // b=0 deformed K slab only
    u16*   pvc  = (u16*)(ws + alloc((size_t)16384*256*2));      // b=0 deformed V slab only
    u16*   qdH  = (u16*)(ws + alloc((size_t)16384*32*2));
    u16*   qdW  = (u16*)(ws + alloc((size_t)16384*32*2));
    u16*   kdW  = (u16*)(ws + alloc((size_t)16384*32*2));
    u16*   vdW  = (u16*)(ws + alloc((size_t)16384*256*2));      // [H][W][256]
    u16*   attbH= (u16*)(ws + alloc((size_t)4*128*128*128*2));  // [B][H][W][128]
    u16*   attbW= (u16*)(ws + alloc((size_t)4*128*128*128*2));
    u16*   T    = (u16*)(ws + alloc((size_t)4*128*128*256*2));  // [B][W][Hout][C] bf16
    u16*   WH   = (u16*)(ws + alloc((size_t)320*256*2));        // weight hi bf16
    u16*   WLo  = (u16*)(ws + alloc((size_t)320*256*2));        // weight lo bf16
    float* bias = (float*)(ws + alloc(320*4));
    // aliases (all within the workspace; d_out is NEVER used as scratch):
    u16*   xb   = T;                       // xb dead after k_proj_mfma; T written by k_outcol
    float* SH   = (float*)T;               // SH [B][W][H][128] f32 == 33.5 MB == sizeof(T)
    float* SWa  = (float*)attbH;           // SW rows w<64  live inside attbH bytes (f32)
    float* SWb  = (float*)attbW;           // SW rows w>=64 live inside attbW bytes (f32)

    k_detect   <<<1, 256, 0, stream>>>(x, flag);
    k_setup    <<<1, 256, 0, stream>>>(off, dX, dY, d_out, flag);
    k_wconv    <<<320, 256, 0, stream>>>(Wq, Wk, Wv, bq, bk, bv, WH, WLo, bias, flag);
    k_xconv    <<<1024, 256, 0, stream>>>(x, xb, flag);
    k_proj_mfma<<<1280, 256, 0, stream>>>(xb, WH, WLo, bias, pqk, pvx);
    k_sample   <<<32768, 320, 0, stream>>>(pqk, pvx, dX, dY, qdH, pkc, pvc, qdW, kdW, vdW);
    k_scores   <<<1024, 256, 0, stream>>>(pqk, pkc, qdH, qdW, kdW, SH, SWa, SWb);
    k_softmax  <<<512, 256, 0, stream>>>(SH, SWa, SWb, attbH, attbW);
    k_outcol   <<<dim3(512, 2), 256, 0, stream>>>(pvc, pvx, attbH, T);
    k_outrow   <<<dim3(512, 2), 256, 0, stream>>>(pvx, vdW, attbW, T, x, gamma, d_out, flag);
    (void)in_sizes; (void)n_in; (void)out_size; (void)ws_size;
}

// Round 15
// 407.401 us; speedup vs baseline: 1.2343x; 1.0505x over previous
//
#include <hip/hip_runtime.h>
#include <hip/hip_bf16.h>

typedef unsigned short u16;
typedef unsigned int   u32;
typedef short bf16x8 __attribute__((ext_vector_type(8)));
typedef float f32x4  __attribute__((ext_vector_type(4)));

__device__ __forceinline__ float b2f(u16 u) {
    return __uint_as_float(((u32)u) << 16);
}
__device__ __forceinline__ u16 f2b(float f) {
    __hip_bfloat16 h = __float2bfloat16(f);
    u16 r; __builtin_memcpy(&r, &h, 2); return r;
}
// dtype-adaptive input load / output store (flag: 1 = fp32, 0 = bf16)
__device__ __forceinline__ float ldin(const void* p, size_t i, bool f32) {
    return f32 ? ((const float*)p)[i] : b2f(((const u16*)p)[i]);
}
__device__ __forceinline__ void stout(void* p, size_t i, float v, bool f32) {
    if (f32) ((float*)p)[i] = v; else ((u16*)p)[i] = f2b(v);
}

// ---------------------------------------------------------------------------
// K-1: dtype detector (fp32 low halves ~ uniform bits -> bf16-NaN patterns).
// ---------------------------------------------------------------------------
__global__ __launch_bounds__(256) void k_detect(const void* __restrict__ xraw, int* __restrict__ flag)
{
    const uint4* xv = (const uint4*)xraw;
    int t = threadIdx.x;
    int cnt = 0;
    for (int i = t; i < 8192; i += 256) {
        uint4 u = xv[i];
        u32 uu[4] = {u.x, u.y, u.z, u.w};
        #pragma unroll
        for (int q = 0; q < 4; ++q) {
            u16 a = (u16)(uu[q] & 0xffff), b = (u16)(uu[q] >> 16);
            if ((a & 0x7F80u) == 0x7F80u && (a & 0x007Fu) != 0) cnt++;
            if ((b & 0x7F80u) == 0x7F80u && (b & 0x007Fu) != 0) cnt++;
        }
    }
    __shared__ int red[256];
    red[t] = cnt; __syncthreads();
    for (int st = 128; st > 0; st >>= 1) {
        if (t < st) red[t] += red[t + st];
        __syncthreads();
    }
    if (t == 0) flag[0] = (red[0] > 16) ? 1 : 0;
}

// ---------------------------------------------------------------------------
// K0: pooled offset lines (dX, dY) + regloss.  offsets [2][131][131]
// ---------------------------------------------------------------------------
__global__ __launch_bounds__(256) void k_setup(const void* __restrict__ off,
                                               float* __restrict__ dX, float* __restrict__ dY,
                                               void* __restrict__ out, const int* __restrict__ flag) {
    bool f32 = flag[0] != 0;
    int t = threadIdx.x;
    if (t < 129) {
        for (int ch = 0; ch < 2; ++ch) {
            float s1 = 0.f, s2 = 0.f;
            for (int i = 0; i < 3; ++i)
                for (int j = 0; j < 3; ++j) {
                    s1 += ldin(off, ch*17161 + (t+i)*131 + (64+j), f32);
                    s2 += ldin(off, ch*17161 + (64+i)*131 + (t+j), f32);
                }
            dX[t*2 + ch] = s1 * (1.0f/9.0f);
            dY[t*2 + ch] = s2 * (1.0f/9.0f);
        }
    }
    float s = 0.f;
    for (int idx = t; idx < 17161; idx += 256) {
        float d = ldin(off, idx, f32) - ldin(off, 17161 + idx, f32);
        s += d * d * (1.0f/17161.0f);
    }
    for (int idx = t; idx < 34060; idx += 256) {
        int ch = idx / 17030;
        int rem = idx - ch*17030;
        int r = rem / 131, c = rem - r*131;
        float a = ldin(off, ch*17161 + r*131 + c, f32);
        float b = ldin(off, ch*17161 + (r+1)*131 + c, f32);
        float d = a - b;
        s += d * d * (1.0f/34060.0f);
    }
    __shared__ float red[256];
    red[t] = s; __syncthreads();
    for (int st = 128; st > 0; st >>= 1) {
        if (t < st) red[t] += red[t + st];
        __syncthreads();
    }
    if (t == 0) {
        float v = red[0];
        if (!(v == v)) v = -299.f;
        stout(out, (size_t)16777216, v, f32);
    }
}

// ---------------------------------------------------------------------------
// K0b: weight conversion, ONCE.  W rows stacked [Wq(32) | Wk(32) | Wv(256)]
// -> WH/WLo bf16 [320][256], bias fp32 [320].
// ---------------------------------------------------------------------------
__global__ __launch_bounds__(256) void k_wconv(
    const void* __restrict__ Wq, const void* __restrict__ Wk, const void* __restrict__ Wv,
    const void* __restrict__ bq, const void* __restrict__ bk, const void* __restrict__ bv,
    u16* __restrict__ WH, u16* __restrict__ WLo, float* __restrict__ bias,
    const int* __restrict__ flag)
{
    bool f32 = flag[0] != 0;
    int idx = blockIdx.x * 256 + threadIdx.x;          // grid 320 -> 81920
    if (idx < 81920) {
        int row = idx >> 8;
        int col = idx & 255;
        const void* src; int r;
        if (row < 32)      { src = Wq; r = row; }
        else if (row < 64) { src = Wk; r = row - 32; }
        else               { src = Wv; r = row - 64; }
        float wv = ldin(src, (size_t)r*256 + col, f32);
        u16 hi = f2b(wv);
        WH [idx] = hi;
        WLo[idx] = f2b(wv - b2f(hi));
    }
    if (blockIdx.x == 0 && threadIdx.x < 320) {
        int row = threadIdx.x;
        const void* src; int r;
        if (row < 32)      { src = bq; r = row; }
        else if (row < 64) { src = bk; r = row - 32; }
        else               { src = bv; r = row - 64; }
        bias[row] = ldin(src, r, f32);
    }
}

// ---------------------------------------------------------------------------
// K0c: x transpose+convert via LDS tile, ONCE.  x [B][C][HW] -> xb [B*HW][256].
// ---------------------------------------------------------------------------
__global__ __launch_bounds__(256) void k_xconv(const void* __restrict__ xraw,
                                               u16* __restrict__ xb,
                                               const int* __restrict__ flag)
{
    bool f32 = flag[0] != 0;
    int t = threadIdx.x;
    int gp = blockIdx.x * 64;            // global pixel base
    int b  = gp >> 14;
    int p0 = gp & 16383;

    __shared__ u32 lt[64*131];

    int p  = t & 63;
    int co = t >> 6;                     // 0..3
    size_t xbase = ((size_t)b*256)*16384 + p0 + p;
    #pragma unroll
    for (int i = 0; i < 32; ++i) {
        int cp = i*4 + co;               // channel pair 0..127
        u16 lo, hi;
        if (f32) {
            const float* xf = (const float*)xraw;
            lo = f2b(xf[xbase + (size_t)(2*cp)*16384]);
            hi = f2b(xf[xbase + (size_t)(2*cp+1)*16384]);
        } else {
            const u16* xu = (const u16*)xraw;
            lo = xu[xbase + (size_t)(2*cp)*16384];
            hi = xu[xbase + (size_t)(2*cp+1)*16384];
        }
        lt[p*131 + cp] = (u32)lo | ((u32)hi << 16);
    }
    __syncthreads();
    int u4 = t & 31;                     // uint4 index within 512B row
    int pr = t >> 5;                     // 0..7
    #pragma unroll
    for (int pass = 0; pass < 8; ++pass) {
        int pp = pass*8 + pr;
        u32 w0 = lt[pp*131 + u4*4 + 0];
        u32 w1 = lt[pp*131 + u4*4 + 1];
        u32 w2 = lt[pp*131 + u4*4 + 2];
        u32 w3 = lt[pp*131 + u4*4 + 3];
        *reinterpret_cast<uint4*>(xb + ((size_t)(gp + pp))*256 + u4*8) =
            make_uint4(w0, w1, w2, w3);
    }
}

// ---------------------------------------------------------------------------
// K1: MFMA projections, weights staged in LDS in FRAGMENT ORDER.
// wf[kc][ot2][hl][lane] 16B fragments: staging writes are wave-contiguous
// (conflict-free ds_write_b128), loop reads are lane*16 contiguous
// (conflict-free ds_read_b128) -> removes the 64-serial-L2-load critical
// path that pinned every global-weight variant at 73-86us.
// XCD-aware mapping (R8) for xb L2 reuse kept.  LDS 64KB, 2 blocks/CU.
// ---------------------------------------------------------------------------
__global__ __launch_bounds__(256, 2) void k_proj_mfma(
    const u16* __restrict__ xb,
    const u16* __restrict__ WH, const u16* __restrict__ WLo,
    const float* __restrict__ bias,
    u16* __restrict__ pqk, u16* __restrict__ pvx)
{
    int t = threadIdx.x;
    int bid = blockIdx.x;                // 0..1279
    int xcd = bid & 7;
    int s   = bid >> 3;                  // 0..159
    int ot  = s % 5;                     // output slice
    int gpg = (s / 5) * 8 + xcd;         // pixel group 0..255
    int gp = gpg * 256;                  // global pixel base (b*16384 + p0)
    int b  = gp >> 14;
    int p0 = gp & 16383;
    int o_base = ot * 64;

    int wid = t >> 6, lane = t & 63;
    int quad = lane >> 4, n = lane & 15;

    __shared__ uint4 wf[4096];           // [kc][ot2][hl][lane] = 64 KB

    // stage weight fragments (16 per thread; LDS writes wave-contiguous)
    #pragma unroll
    for (int i = 0; i < 16; ++i) {
        int idx = i*256 + t;
        int ln  = idx & 63;
        int hl  = (idx >> 6) & 1;
        int ot2 = (idx >> 7) & 3;
        int kc  = idx >> 9;
        const u16* src = (hl ? WLo : WH)
            + ((size_t)(o_base + ot2*16 + (ln & 15)))*256 + kc*32 + (ln >> 4)*8;
        wf[idx] = *reinterpret_cast<const uint4*>(src);
    }

    const u16* xr = xb + ((size_t)(gp + wid*64 + n)) * 256 + quad*8;
    // preload all xb fragments (this lane's full row slice)
    bf16x8 bf[8][4];
    #pragma unroll
    for (int kc = 0; kc < 8; ++kc)
        #pragma unroll
        for (int pt = 0; pt < 4; ++pt)
            bf[kc][pt] = *reinterpret_cast<const bf16x8*>(xr + (size_t)pt*16*256 + kc*32);

    __syncthreads();

    f32x4 acc[4][4];
    #pragma unroll
    for (int i = 0; i < 4; ++i)
        #pragma unroll
        for (int j = 0; j < 4; ++j) acc[i][j] = (f32x4){0.f, 0.f, 0.f, 0.f};

    #pragma unroll
    for (int kc = 0; kc < 8; ++kc) {
        #pragma unroll
        for (int ot2 = 0; ot2 < 4; ++ot2) {
            int fb = ((kc*4 + ot2)*2)*64 + lane;
            bf16x8 ah = *reinterpret_cast<const bf16x8*>(&wf[fb]);
            bf16x8 al = *reinterpret_cast<const bf16x8*>(&wf[fb + 64]);
            #pragma unroll
            for (int pt = 0; pt < 4; ++pt) {
                acc[ot2][pt] = __builtin_amdgcn_mfma_f32_16x16x32_bf16(ah, bf[kc][pt], acc[ot2][pt], 0, 0, 0);
                acc[ot2][pt] = __builtin_amdgcn_mfma_f32_16x16x32_bf16(al, bf[kc][pt], acc[ot2][pt], 0, 0, 0);
            }
        }
    }
    #pragma unroll
    for (int ot2 = 0; ot2 < 4; ++ot2) {
        int o_l = ot2*16 + quad*4;
        int og  = o_base + o_l;
        float b0 = bias[og], b1 = bias[og+1], b2 = bias[og+2], b3 = bias[og+3];
        #pragma unroll
        for (int pt = 0; pt < 4; ++pt) {
            f32x4 a = acc[ot2][pt];
            int px = p0 + wid*64 + pt*16 + n;
            u32 w0 = (u32)f2b(a[0] + b0) | ((u32)f2b(a[1] + b1) << 16);
            u32 w1 = (u32)f2b(a[2] + b2) | ((u32)f2b(a[3] + b3) << 16);
            u16* dst;
            if (ot == 0) dst = pqk + ((size_t)(b*16384 + px))*64  + o_l;
            else         dst = pvx + ((size_t)(b*16384 + px))*256 + (o_base - 64 + o_l);
            *reinterpret_cast<uint2*>(dst) = make_uint2(w0, w1);
        }
    }
}

// ---------------------------------------------------------------------------
// K2: deformed bilinear sampling for batch 0.
// ---------------------------------------------------------------------------
__global__ __launch_bounds__(320) void k_sample(
    const u16* __restrict__ pqk, const u16* __restrict__ pvx,
    const float* __restrict__ dX, const float* __restrict__ dY,
    u16* __restrict__ qdH, u16* __restrict__ pkc, u16* __restrict__ pvc,
    u16* __restrict__ qdW, u16* __restrict__ kdW, u16* __restrict__ vdW)
{
    int bid = blockIdx.x;
    int variant = bid >> 14;
    int pt = bid & 16383;
    int t = threadIdx.x;
    int w, h;
    float xn, yn;
    if (variant == 0) {
        w = pt >> 7; h = pt & 127;
        xn = (-1.0f + (float)w     * (2.0f/128.0f)) + dX[(h+1)*2 + 0];
        yn = (-1.0f + (float)(h+1) * (2.0f/128.0f)) + dX[(h+1)*2 + 1];
    } else {
        h = pt >> 7; w = pt & 127;
        xn = (-1.0f + (float)(w+1) * (2.0f/128.0f)) + dY[(w+1)*2 + 0];
        yn = (-1.0f + (float)h     * (2.0f/128.0f)) + dY[(w+1)*2 + 1];
    }
    float fx = (xn + 1.0f) * 0.5f * 127.0f;
    float fy = (yn + 1.0f) * 0.5f * 127.0f;
    float x0f = floorf(fx), y0f = floorf(fy);
    float wx = fx - x0f, wy = fy - y0f;

    float wt[4]; int xi[4], yi[4]; bool vd[4];
    {
        float xs[2]  = { x0f, x0f + 1.0f };
        float ys[2]  = { y0f, y0f + 1.0f };
        float wxs[2] = { 1.0f - wx, wx };
        float wys[2] = { 1.0f - wy, wy };
        #pragma unroll
        for (int jy = 0; jy < 2; ++jy)
            #pragma unroll
            for (int jx = 0; jx < 2; ++jx) {
                int k = jy*2 + jx;
                vd[k] = (xs[jx] >= 0.f) && (xs[jx] < 128.f) && (ys[jy] >= 0.f) && (ys[jy] < 128.f);
                wt[k] = wxs[jx] * wys[jy];
                xi[k] = (int)fminf(fmaxf(xs[jx], 0.f), 127.f);
                yi[k] = (int)fminf(fmaxf(ys[jy], 0.f), 127.f);
            }
    }
    float val = 0.f;
    if (t < 64) {
        #pragma unroll
        for (int k = 0; k < 4; ++k)
            if (vd[k]) val += wt[k] * b2f(pqk[(size_t)(yi[k]*128 + xi[k])*64 + t]);
        if (t < 32) {
            if (variant == 0) qdH[(size_t)pt*32 + t] = f2b(val);
            else              qdW[(size_t)pt*32 + t] = f2b(val);
        } else {
            int c = t - 32;
            if (variant == 0) pkc[(size_t)pt*32 + c] = f2b(val);
            else              kdW[(size_t)pt*32 + c] = f2b(val);
        }
    } else {
        int c = t - 64;
        #pragma unroll
        for (int k = 0; k < 4; ++k)
            if (vd[k]) val += wt[k] * b2f(pvx[(size_t)(yi[k]*128 + xi[k])*256 + c]);
        if (variant == 0) pvc[(size_t)pt*256 + c] = f2b(val);
        else              vdW[(size_t)pt*256 + c] = f2b(val);
    }
}

// ---------------------------------------------------------------------------
// K3a: raw attention scores via MFMA.  1024 blocks = kind(2) x b(4) x line(128).
// ---------------------------------------------------------------------------
__global__ __launch_bounds__(256) void k_scores(
    const u16* __restrict__ pqk, const u16* __restrict__ pkc,
    const u16* __restrict__ qdH, const u16* __restrict__ qdW, const u16* __restrict__ kdW,
    float* __restrict__ SH, float* __restrict__ SWa, float* __restrict__ SWb)
{
    int bid = blockIdx.x;
    int kind = bid >> 9;
    int b    = (bid >> 7) & 3;
    int line = bid & 127;
    int t = threadIdx.x;
    int wid = t >> 6, lane = t & 63;
    int n16 = lane & 15, quad = lane >> 4;

    const u16 *Qb, *Kb; int qstride, kstride;
    float* Sb = nullptr;
    float* s_lo = nullptr; float* s_hi = nullptr;
    if (kind == 0) {                 // column scores, line = w
        if (b == 0) { Qb = qdH + (size_t)line*4096;                 qstride = 32;
                      Kb = pkc + (size_t)line*4096;                 kstride = 32;   }
        else        { Qb = pqk + ((size_t)(b*16384 + line))*64;     qstride = 8192;
                      Kb = Qb + 32;                                 kstride = 8192; }
        Sb = SH + ((size_t)(b*128 + line))*16384;
    } else {                          // row scores, line = h
        if (b == 0) { Qb = qdW + (size_t)line*4096;                 qstride = 32;
                      Kb = kdW + (size_t)line*4096;                 kstride = 32; }
        else        { Qb = pqk + ((size_t)(b*16384 + line*128))*64; qstride = 64;
                      Kb = Qb + 32;                                 kstride = 64; }
        size_t base = (size_t)(b*128 + line)*8192;
        s_lo = SWa + base;            // rows 0..63
        s_hi = SWb + base;            // rows 64..127 (index m-64)
    }

    bf16x8 af[2];
    #pragma unroll
    for (int m2 = 0; m2 < 2; ++m2)
        af[m2] = *reinterpret_cast<const bf16x8*>(
            Qb + (size_t)(wid*32 + m2*16 + n16)*qstride + quad*8);

    #pragma unroll
    for (int nt = 0; nt < 8; ++nt) {
        bf16x8 bf = *reinterpret_cast<const bf16x8*>(
            Kb + (size_t)(nt*16 + n16)*kstride + quad*8);
        f32x4 a0 = (f32x4){0.f,0.f,0.f,0.f};
        f32x4 a1 = (f32x4){0.f,0.f,0.f,0.f};
        a0 = __builtin_amdgcn_mfma_f32_16x16x32_bf16(af[0], bf, a0, 0, 0, 0);
        a1 = __builtin_amdgcn_mfma_f32_16x16x32_bf16(af[1], bf, a1, 0, 0, 0);
        int j = nt*16 + n16;
        int m0 = wid*32 + quad*4;
        if (kind == 0) {
            #pragma unroll
            for (int r = 0; r < 4; ++r) {
                Sb[(size_t)(m0 + r)*128 + j]      = a0[r];
                Sb[(size_t)(m0 + 16 + r)*128 + j] = a1[r];
            }
        } else {
            #pragma unroll
            for (int r = 0; r < 4; ++r) {
                int mA = m0 + r, mB = m0 + 16 + r;
                float* pA = (mA < 64) ? (s_lo + (size_t)mA*128 + j)
                                      : (s_hi + (size_t)(mA - 64)*128 + j);
                float* pB = (mB < 64) ? (s_lo + (size_t)mB*128 + j)
                                      : (s_hi + (size_t)(mB - 64)*128 + j);
                *pA = a0[r];
                *pB = a1[r];
            }
        }
    }
}

// ---------------------------------------------------------------------------
// K3b: joint softmax, register-resident.  block (b,h), 256 thr = (kind, w).
// ---------------------------------------------------------------------------
__global__ __launch_bounds__(256) void k_softmax(
    const float* __restrict__ SH, const float* __restrict__ SWa, const float* __restrict__ SWb,
    u16* __restrict__ attbH, u16* __restrict__ attbW)
{
    int b = blockIdx.x >> 7, h = blockIdx.x & 127;
    int t = threadIdx.x;
    int kind = t >> 7, w = t & 127;
    __shared__ float mh[256], zh[256];
    __shared__ float Mw[128], Iw[128];

    const float* src;
    if (kind == 0) {
        src = SH + (((size_t)(b*128 + w))*128 + h)*128;
    } else {
        size_t base = (size_t)(b*128 + h)*8192;
        src = (w < 64) ? (SWa + base + (size_t)w*128)
                       : (SWb + base + (size_t)(w - 64)*128);
    }
    const float4* s4 = reinterpret_cast<const float4*>(src);

    float4 row[32];
    #pragma unroll
    for (int q = 0; q < 32; ++q) row[q] = s4[q];

    if (kind == 0) {
        #pragma unroll
        for (int q = 0; q < 32; ++q) {
            float4 v = row[q];
            if (q*4     == h) v.x = -INFINITY;
            if (q*4 + 1 == h) v.y = -INFINITY;
            if (q*4 + 2 == h) v.z = -INFINITY;
            if (q*4 + 3 == h) v.w = -INFINITY;
            row[q] = v;
        }
    }

    float m = -INFINITY;
    #pragma unroll
    for (int q = 0; q < 32; ++q) {
        float4 v = row[q];
        m = fmaxf(m, fmaxf(fmaxf(v.x, v.y), fmaxf(v.z, v.w)));
    }
    mh[t] = m;
    __syncthreads();
    if (t < 128) Mw[t] = fmaxf(mh[t], mh[128 + t]);
    __syncthreads();

    float M = Mw[w];
    float Z = 0.f;
    #pragma unroll
    for (int q = 0; q < 32; ++q) {
        float4 v = row[q];
        Z += __expf(v.x - M) + __expf(v.y - M) + __expf(v.z - M) + __expf(v.w - M);
    }
    zh[t] = Z;
    __syncthreads();
    if (t < 128) Iw[t] = 1.0f / (zh[t] + zh[128 + t]);
    __syncthreads();

    float I = Iw[w];
    u16* dst = (kind == 0)
        ? attbH + (((size_t)(b*128 + h))*128 + w)*128
        : attbW + (((size_t)(b*128 + h))*128 + w)*128;
    #pragma unroll
    for (int q = 0; q < 16; ++q) {
        float4 v0 = row[2*q], v1 = row[2*q + 1];
        u32 o0 = (u32)f2b(__expf(v0.x - M) * I) | ((u32)f2b(__expf(v0.y - M) * I) << 16);
        u32 o1 = (u32)f2b(__expf(v0.z - M) * I) | ((u32)f2b(__expf(v0.w - M) * I) << 16);
        u32 o2 = (u32)f2b(__expf(v1.x - M) * I) | ((u32)f2b(__expf(v1.y - M) * I) << 16);
        u32 o3 = (u32)f2b(__expf(v1.z - M) * I) | ((u32)f2b(__expf(v1.w - M) * I) << 16);
        *reinterpret_cast<uint4*>(dst + q*8) = make_uint4(o0, o1, o2, o3);
    }
}

// ---------------------------------------------------------------------------
// LDS V-transpose staging shared by K4/K5:
// vt[c][m] = pack(V[row 2m][c], V[row 2m+1][c]) as u32, LDS row stride 68 u32.
// vstride = u16 distance between consecutive V rows in global memory.
// ---------------------------------------------------------------------------
__device__ __forceinline__ void stage_vt(u32* vt, const u16* Vsrc, size_t vstride, int t)
{
    int j2 = t & 63;                 // row pair index
    int c8 = (t >> 6) * 8;           // col octet base
    const u16* r0 = Vsrc + (size_t)(2*j2)*vstride;
    const u16* r1 = r0 + vstride;
    #pragma unroll
    for (int i = 0; i < 4; ++i) {
        int c = i*32 + c8;
        uint4 a  = *reinterpret_cast<const uint4*>(r0 + c);
        uint4 bb = *reinterpret_cast<const uint4*>(r1 + c);
        u32 au[4] = {a.x, a.y, a.z, a.w};
        u32 bu[4] = {bb.x, bb.y, bb.z, bb.w};
        #pragma unroll
        for (int e = 0; e < 4; ++e) {
            vt[(c + 2*e    )*68 + j2] = (au[e] & 0xffffu) | (bu[e] << 16);
            vt[(c + 2*e + 1)*68 + j2] = (au[e] >> 16)     | (bu[e] & 0xffff0000u);
        }
    }
}

// ---------------------------------------------------------------------------
// K4: column aggregation via MFMA, V via LDS transpose.
// T[b][w][k][c] = sum_h att * V;  V from pvc slab (b=0) or pvx columns (b>=1).
// ---------------------------------------------------------------------------
__global__ __launch_bounds__(256, 2) void k_outcol(const u16* __restrict__ pvc,
    const u16* __restrict__ pvx, const u16* __restrict__ attbH, u16* __restrict__ T)
{
    int b = blockIdx.x >> 7, w = blockIdx.x & 127;
    int half = blockIdx.y;
    int t = threadIdx.x;
    int wid = t >> 6, lane = t & 63;
    int n16 = lane & 15, quad = lane >> 4;

    __shared__ u32 vt[128*68];

    const u16* Abase = attbH + ((size_t)b*128)*16384 + (size_t)w*128;
    bf16x8 af[2][4];
    #pragma unroll
    for (int m2 = 0; m2 < 2; ++m2)
        #pragma unroll
        for (int ks = 0; ks < 4; ++ks)
            af[m2][ks] = *reinterpret_cast<const bf16x8*>(
                Abase + (size_t)(wid*32 + m2*16 + n16)*16384 + ks*32 + quad*8);

    if (b == 0)
        stage_vt(vt, pvc + (size_t)w*128*256 + half*128, 256, t);
    else
        stage_vt(vt, pvx + ((size_t)(b*16384 + w))*256 + half*128, 32768, t);
    __syncthreads();

    f32x4 acc[2][8];
    #pragma unroll
    for (int m2 = 0; m2 < 2; ++m2)
        #pragma unroll
        for (int nt = 0; nt < 8; ++nt) acc[m2][nt] = (f32x4){0.f,0.f,0.f,0.f};

    #pragma unroll
    for (int nt = 0; nt < 8; ++nt) {
        int c = nt*16 + n16;
        #pragma unroll
        for (int ks = 0; ks < 4; ++ks) {
            bf16x8 bfv = *reinterpret_cast<const bf16x8*>(&vt[c*68 + ks*16 + quad*4]);
            acc[0][nt] = __builtin_amdgcn_mfma_f32_16x16x32_bf16(af[0][ks], bfv, acc[0][nt], 0, 0, 0);
            acc[1][nt] = __builtin_amdgcn_mfma_f32_16x16x32_bf16(af[1][ks], bfv, acc[1][nt], 0, 0, 0);
        }
    }

    u16* Tbase = T + (((size_t)(b*128 + w))*128)*256 + half*128;
    #pragma unroll
    for (int m2 = 0; m2 < 2; ++m2) {
        int k0 = wid*32 + m2*16 + quad*4;
        #pragma unroll
        for (int nt = 0; nt < 8; ++nt) {
            int c = nt*16 + n16;
            f32x4 a = acc[m2][nt];
            #pragma unroll
            for (int r = 0; r < 4; ++r)
                Tbase[(size_t)(k0 + r)*256 + c] = f2b(a[r]);
        }
    }
}

// ---------------------------------------------------------------------------
// K5: row aggregation via MFMA + epilogue, V via LDS transpose.
// ---------------------------------------------------------------------------
__global__ __launch_bounds__(256, 2) void k_outrow(const u16* __restrict__ pvx, const u16* __restrict__ vdW,
    const u16* __restrict__ attbW, const u16* __restrict__ T, const void* __restrict__ xraw,
    const void* __restrict__ gamma, void* __restrict__ out, const int* __restrict__ flag)
{
    bool f32 = flag[0] != 0;
    int b = blockIdx.x >> 7, h = blockIdx.x & 127;
    int half = blockIdx.y;
    int t = threadIdx.x;
    int wid = t >> 6, lane = t & 63;
    int n16 = lane & 15, quad = lane >> 4;

    __shared__ u32 vt[128*68];

    const u16* Abase = attbW + ((size_t)(b*128 + h))*16384;
    bf16x8 af[2][4];
    #pragma unroll
    for (int m2 = 0; m2 < 2; ++m2)
        #pragma unroll
        for (int ks = 0; ks < 4; ++ks)
            af[m2][ks] = *reinterpret_cast<const bf16x8*>(
                Abase + (size_t)(wid*32 + m2*16 + n16)*128 + ks*32 + quad*8);

    const u16* Vsrc = ((b == 0) ? (vdW + (size_t)h*128*256)
                                : (pvx + ((size_t)b*16384 + h*128)*256)) + half*128;
    stage_vt(vt, Vsrc, 256, t);
    __syncthreads();

    f32x4 acc[2][8];
    #pragma unroll
    for (int m2 = 0; m2 < 2; ++m2)
        #pragma unroll
        for (int nt = 0; nt < 8; ++nt) acc[m2][nt] = (f32x4){0.f,0.f,0.f,0.f};

    #pragma unroll
    for (int nt = 0; nt < 8; ++nt) {
        int c = nt*16 + n16;
        #pragma unroll
        for (int ks = 0; ks < 4; ++ks) {
            bf16x8 bfv = *reinterpret_cast<const bf16x8*>(&vt[c*68 + ks*16 + quad*4]);
            acc[0][nt] = __builtin_amdgcn_mfma_f32_16x16x32_bf16(af[0][ks], bfv, acc[0][nt], 0, 0, 0);
            acc[1][nt] = __builtin_amdgcn_mfma_f32_16x16x32_bf16(af[1][ks], bfv, acc[1][nt], 0, 0, 0);
        }
    }

    float gm = ldin(gamma, 0, f32);
    const u16* Tbase = T + ((size_t)(b*128))*128*256 + (size_t)h*256 + half*128;

    #pragma unroll
    for (int m2 = 0; m2 < 2; ++m2) {
        int k0 = wid*32 + m2*16 + quad*4;
        #pragma unroll
        for (int nt = 0; nt < 8; ++nt) {
            int c = nt*16 + n16;
            int cg = half*128 + c;
            f32x4 a = acc[m2][nt];
            float r[4];
            #pragma unroll
            for (int i = 0; i < 4; ++i) {
                float hst = b2f(Tbase[(size_t)(k0 + i)*32768 + c]);
                r[i] = gm * (hst + a[i]);
            }
            size_t base = ((size_t)(b*256 + cg)*128 + h)*128 + k0;
            if (f32) {
                float4 xx = *reinterpret_cast<const float4*>((const float*)xraw + base);
                float4 rr;
                rr.x = r[0] + xx.x; rr.y = r[1] + xx.y;
                rr.z = r[2] + xx.z; rr.w = r[3] + xx.w;
                if (!(rr.x == rr.x)) rr.x = -299.f;
                if (!(rr.y == rr.y)) rr.y = -299.f;
                if (!(rr.z == rr.z)) rr.z = -299.f;
                if (!(rr.w == rr.w)) rr.w = -299.f;
                *reinterpret_cast<float4*>((float*)out + base) = rr;
            } else {
                uint2 xx = *reinterpret_cast<const uint2*>((const u16*)xraw + base);
                u32 xu[2] = { xx.x, xx.y };
                u32 ou[2];
                #pragma unroll
                for (int p2 = 0; p2 < 2; ++p2) {
                    float xlo = __uint_as_float(xu[p2] << 16);
                    float xhi = __uint_as_float(xu[p2] & 0xffff0000u);
                    float olo = r[p2*2]   + xlo;
                    float ohi = r[p2*2+1] + xhi;
                    if (!(olo == olo)) olo = -299.f;
                    if (!(ohi == ohi)) ohi = -299.f;
                    ou[p2] = (u32)f2b(olo) | ((u32)f2b(ohi) << 16);
                }
                *reinterpret_cast<uint2*>((u16*)out + base) = make_uint2(ou[0], ou[1]);
            }
        }
    }
}

// ---------------------------------------------------------------------------
extern "C" void kernel_launch(void* const* d_in, const int* in_sizes, int n_in,
                              void* d_out, int out_size, void* d_ws, size_t ws_size,
                              hipStream_t stream)
{
    const void* x     = d_in[0];
    const void* Wq    = d_in[1];
    const void* bq    = d_in[2];
    const void* Wk    = d_in[3];
    const void* bk    = d_in[4];
    const void* Wv    = d_in[5];
    const void* bv    = d_in[6];
    const void* gamma = d_in[7];
    const void* off   = d_in[8];

    char* ws = (char*)d_ws;
    size_t o = 0;
    auto alloc = [&](size_t bytes) { size_t r = o; o += (bytes + 255) & ~(size_t)255; return r; };
    int*   flag = (int*)(ws + alloc(256));
    float* dX   = (float*)(ws + alloc(129*2*4));
    float* dY   = (float*)(ws + alloc(129*2*4));
    u16*   pqk  = (u16*)(ws + alloc((size_t)4*16384*64*2));     // [B][HW][64]
    u16*   pvx  = (u16*)(ws + alloc((size_t)4*16384*256*2));    // [B][HW][256]
    u16*   pkc  = (u16*)(ws + alloc((size_t)16384*32*2));       // b=0 deformed K slab only
    u16*   pvc  = (u16*)(ws + alloc((size_t)16384*256*2));      // b=0 deformed V slab only
    u16*   qdH  = (u16*)(ws + alloc((size_t)16384*32*2));
    u16*   qdW  = (u16*)(ws + alloc((size_t)16384*32*2));
    u16*   kdW  = (u16*)(ws + alloc((size_t)16384*32*2));
    u16*   vdW  = (u16*)(ws + alloc((size_t)16384*256*2));      // [H][W][256]
    u16*   attbH= (u16*)(ws + alloc((size_t)4*128*128*128*2));  // [B][H][W][128]
    u16*   attbW= (u16*)(ws + alloc((size_t)4*128*128*128*2));
    u16*   T    = (u16*)(ws + alloc((size_t)4*128*128*256*2));  // [B][W][Hout][C] bf16
    u16*   WH   = (u16*)(ws + alloc((size_t)320*256*2));        // weight hi bf16
    u16*   WLo  = (u16*)(ws + alloc((size_t)320*256*2));        // weight lo bf16
    float* bias = (float*)(ws + alloc(320*4));
    // aliases (all within the workspace; d_out is NEVER used as scratch):
    u16*   xb   = T;                       // xb dead after k_proj_mfma; T written by k_outcol
    float* SH   = (float*)T;               // SH [B][W][H][128] f32 == 33.5 MB == sizeof(T)
    float* SWa  = (float*)attbH;           // SW rows w<64  live inside attbH bytes (f32)
    float* SWb  = (float*)attbW;           // SW rows w>=64 live inside attbW bytes (f32)

    k_detect   <<<1, 256, 0, stream>>>(x, flag);
    k_setup    <<<1, 256, 0, stream>>>(off, dX, dY, d_out, flag);
    k_wconv    <<<320, 256, 0, stream>>>(Wq, Wk, Wv, bq, bk, bv, WH, WLo, bias, flag);
    k_xconv    <<<1024, 256, 0, stream>>>(x, xb, flag);
    k_proj_mfma<<<1280, 256, 0, stream>>>(xb, WH, WLo, bias, pqk, pvx);
    k_sample   <<<32768, 320, 0, stream>>>(pqk, pvx, dX, dY, qdH, pkc, pvc, qdW, kdW, vdW);
    k_scores   <<<1024, 256, 0, stream>>>(pqk, pkc, qdH, qdW, kdW, SH, SWa, SWb);
    k_softmax  <<<512, 256, 0, stream>>>(SH, SWa, SWb, attbH, attbW);
    k_outcol   <<<dim3(512, 2), 256, 0, stream>>>(pvc, pvx, attbH, T);
    k_outrow   <<<dim3(512, 2), 256, 0, stream>>>(pvx, vdW, attbW, T, x, gamma, d_out, flag);
    (void)in_sizes; (void)n_in; (void)out_size; (void)ws_size;
}

// Round 16
// 350.376 us; speedup vs baseline: 1.4352x; 1.1628x over previous
//
#include <hip/hip_runtime.h>
#include <hip/hip_bf16.h>

typedef unsigned short u16;
typedef unsigned int   u32;
typedef short bf16x8 __attribute__((ext_vector_type(8)));
typedef float f32x4  __attribute__((ext_vector_type(4)));

__device__ __forceinline__ float b2f(u16 u) {
    return __uint_as_float(((u32)u) << 16);
}
__device__ __forceinline__ u16 f2b(float f) {
    __hip_bfloat16 h = __float2bfloat16(f);
    u16 r; __builtin_memcpy(&r, &h, 2); return r;
}
// dtype-adaptive input load / output store (flag: 1 = fp32, 0 = bf16)
__device__ __forceinline__ float ldin(const void* p, size_t i, bool f32) {
    return f32 ? ((const float*)p)[i] : b2f(((const u16*)p)[i]);
}
__device__ __forceinline__ void stout(void* p, size_t i, float v, bool f32) {
    if (f32) ((float*)p)[i] = v; else ((u16*)p)[i] = f2b(v);
}

// ---------------------------------------------------------------------------
// K-1: dtype detector (fp32 low halves ~ uniform bits -> bf16-NaN patterns).
// ---------------------------------------------------------------------------
__global__ __launch_bounds__(256) void k_detect(const void* __restrict__ xraw, int* __restrict__ flag)
{
    const uint4* xv = (const uint4*)xraw;
    int t = threadIdx.x;
    int cnt = 0;
    for (int i = t; i < 8192; i += 256) {
        uint4 u = xv[i];
        u32 uu[4] = {u.x, u.y, u.z, u.w};
        #pragma unroll
        for (int q = 0; q < 4; ++q) {
            u16 a = (u16)(uu[q] & 0xffff), b = (u16)(uu[q] >> 16);
            if ((a & 0x7F80u) == 0x7F80u && (a & 0x007Fu) != 0) cnt++;
            if ((b & 0x7F80u) == 0x7F80u && (b & 0x007Fu) != 0) cnt++;
        }
    }
    __shared__ int red[256];
    red[t] = cnt; __syncthreads();
    for (int st = 128; st > 0; st >>= 1) {
        if (t < st) red[t] += red[t + st];
        __syncthreads();
    }
    if (t == 0) flag[0] = (red[0] > 16) ? 1 : 0;
}

// ---------------------------------------------------------------------------
// K0a: parallel setup.  65 blocks:
//  blocks 0..63  — deterministic partial reduction of regloss terms
//  block  64     — pooled offset lines dX/dY
// (old single-block k_setup serialized 51K latency-bound loads on 1 CU
//  = 57us, top kernel at R15.  No atomics: per-block partials keep the
//  graph-replay output bit-deterministic.)
// ---------------------------------------------------------------------------
__global__ __launch_bounds__(256) void k_setup_red(const void* __restrict__ off,
                                                   float* __restrict__ dX, float* __restrict__ dY,
                                                   float* __restrict__ partial,
                                                   const int* __restrict__ flag) {
    bool f32 = flag[0] != 0;
    int t = threadIdx.x;
    int bid = blockIdx.x;
    if (bid == 64) {
        if (t < 129) {
            for (int ch = 0; ch < 2; ++ch) {
                float s1 = 0.f, s2 = 0.f;
                for (int i = 0; i < 3; ++i)
                    for (int j = 0; j < 3; ++j) {
                        s1 += ldin(off, ch*17161 + (t+i)*131 + (64+j), f32);
                        s2 += ldin(off, ch*17161 + (64+i)*131 + (t+j), f32);
                    }
                dX[t*2 + ch] = s1 * (1.0f/9.0f);
                dY[t*2 + ch] = s2 * (1.0f/9.0f);
            }
        }
        return;
    }
    int g = bid*256 + t;                 // 0..16383
    float s = 0.f;
    for (int idx = g; idx < 17161; idx += 16384) {
        float d = ldin(off, idx, f32) - ldin(off, 17161 + idx, f32);
        s += d * d * (1.0f/17161.0f);
    }
    for (int idx = g; idx < 34060; idx += 16384) {
        int ch = idx / 17030;
        int rem = idx - ch*17030;
        int r = rem / 131, c = rem - r*131;
        float a = ldin(off, ch*17161 + r*131 + c, f32);
        float b = ldin(off, ch*17161 + (r+1)*131 + c, f32);
        float d = a - b;
        s += d * d * (1.0f/34060.0f);
    }
    __shared__ float red[256];
    red[t] = s; __syncthreads();
    for (int st = 128; st > 0; st >>= 1) {
        if (t < st) red[t] += red[t + st];
        __syncthreads();
    }
    if (t == 0) partial[bid] = red[0];
}

// ---------------------------------------------------------------------------
// K0a2: final regloss reduction (fixed order -> deterministic) + store.
// ---------------------------------------------------------------------------
__global__ __launch_bounds__(64) void k_setup_fin(const float* __restrict__ partial,
                                                  void* __restrict__ out,
                                                  const int* __restrict__ flag) {
    bool f32 = flag[0] != 0;
    if (threadIdx.x == 0) {
        float v = 0.f;
        for (int i = 0; i < 64; ++i) v += partial[i];
        if (!(v == v)) v = -299.f;
        stout(out, (size_t)16777216, v, f32);
    }
}

// ---------------------------------------------------------------------------
// K0b: weight conversion, ONCE.  W rows stacked [Wq(32) | Wk(32) | Wv(256)]
// -> WH/WLo bf16 [320][256], bias fp32 [320].
// ---------------------------------------------------------------------------
__global__ __launch_bounds__(256) void k_wconv(
    const void* __restrict__ Wq, const void* __restrict__ Wk, const void* __restrict__ Wv,
    const void* __restrict__ bq, const void* __restrict__ bk, const void* __restrict__ bv,
    u16* __restrict__ WH, u16* __restrict__ WLo, float* __restrict__ bias,
    const int* __restrict__ flag)
{
    bool f32 = flag[0] != 0;
    int idx = blockIdx.x * 256 + threadIdx.x;          // grid 320 -> 81920
    if (idx < 81920) {
        int row = idx >> 8;
        int col = idx & 255;
        const void* src; int r;
        if (row < 32)      { src = Wq; r = row; }
        else if (row < 64) { src = Wk; r = row - 32; }
        else               { src = Wv; r = row - 64; }
        float wv = ldin(src, (size_t)r*256 + col, f32);
        u16 hi = f2b(wv);
        WH [idx] = hi;
        WLo[idx] = f2b(wv - b2f(hi));
    }
    if (blockIdx.x == 0 && threadIdx.x < 320) {
        int row = threadIdx.x;
        const void* src; int r;
        if (row < 32)      { src = bq; r = row; }
        else if (row < 64) { src = bk; r = row - 32; }
        else               { src = bv; r = row - 64; }
        bias[row] = ldin(src, r, f32);
    }
}

// ---------------------------------------------------------------------------
// K0c: x transpose+convert via LDS tile, ONCE.  x [B][C][HW] -> xb [B*HW][256].
// ---------------------------------------------------------------------------
__global__ __launch_bounds__(256) void k_xconv(const void* __restrict__ xraw,
                                               u16* __restrict__ xb,
                                               const int* __restrict__ flag)
{
    bool f32 = flag[0] != 0;
    int t = threadIdx.x;
    int gp = blockIdx.x * 64;            // global pixel base
    int b  = gp >> 14;
    int p0 = gp & 16383;

    __shared__ u32 lt[64*131];

    int p  = t & 63;
    int co = t >> 6;                     // 0..3
    size_t xbase = ((size_t)b*256)*16384 + p0 + p;
    #pragma unroll
    for (int i = 0; i < 32; ++i) {
        int cp = i*4 + co;               // channel pair 0..127
        u16 lo, hi;
        if (f32) {
            const float* xf = (const float*)xraw;
            lo = f2b(xf[xbase + (size_t)(2*cp)*16384]);
            hi = f2b(xf[xbase + (size_t)(2*cp+1)*16384]);
        } else {
            const u16* xu = (const u16*)xraw;
            lo = xu[xbase + (size_t)(2*cp)*16384];
            hi = xu[xbase + (size_t)(2*cp+1)*16384];
        }
        lt[p*131 + cp] = (u32)lo | ((u32)hi << 16);
    }
    __syncthreads();
    int u4 = t & 31;                     // uint4 index within 512B row
    int pr = t >> 5;                     // 0..7
    #pragma unroll
    for (int pass = 0; pass < 8; ++pass) {
        int pp = pass*8 + pr;
        u32 w0 = lt[pp*131 + u4*4 + 0];
        u32 w1 = lt[pp*131 + u4*4 + 1];
        u32 w2 = lt[pp*131 + u4*4 + 2];
        u32 w3 = lt[pp*131 + u4*4 + 3];
        *reinterpret_cast<uint4*>(xb + ((size_t)(gp + pp))*256 + u4*8) =
            make_uint4(w0, w1, w2, w3);
    }
}

// ---------------------------------------------------------------------------
// K1: MFMA projections, weights staged in LDS in FRAGMENT ORDER (R14 win).
// XCD-aware mapping (R8) for xb L2 reuse kept.  LDS 64KB, 2 blocks/CU.
// ---------------------------------------------------------------------------
__global__ __launch_bounds__(256, 2) void k_proj_mfma(
    const u16* __restrict__ xb,
    const u16* __restrict__ WH, const u16* __restrict__ WLo,
    const float* __restrict__ bias,
    u16* __restrict__ pqk, u16* __restrict__ pvx)
{
    int t = threadIdx.x;
    int bid = blockIdx.x;                // 0..1279
    int xcd = bid & 7;
    int s   = bid >> 3;                  // 0..159
    int ot  = s % 5;                     // output slice
    int gpg = (s / 5) * 8 + xcd;         // pixel group 0..255
    int gp = gpg * 256;                  // global pixel base (b*16384 + p0)
    int b  = gp >> 14;
    int p0 = gp & 16383;
    int o_base = ot * 64;

    int wid = t >> 6, lane = t & 63;
    int quad = lane >> 4, n = lane & 15;

    __shared__ uint4 wf[4096];           // [kc][ot2][hl][lane] = 64 KB

    // stage weight fragments (16 per thread; LDS writes wave-contiguous)
    #pragma unroll
    for (int i = 0; i < 16; ++i) {
        int idx = i*256 + t;
        int ln  = idx & 63;
        int hl  = (idx >> 6) & 1;
        int ot2 = (idx >> 7) & 3;
        int kc  = idx >> 9;
        const u16* src = (hl ? WLo : WH)
            + ((size_t)(o_base + ot2*16 + (ln & 15)))*256 + kc*32 + (ln >> 4)*8;
        wf[idx] = *reinterpret_cast<const uint4*>(src);
    }

    const u16* xr = xb + ((size_t)(gp + wid*64 + n)) * 256 + quad*8;
    // preload all xb fragments (this lane's full row slice)
    bf16x8 bf[8][4];
    #pragma unroll
    for (int kc = 0; kc < 8; ++kc)
        #pragma unroll
        for (int pt = 0; pt < 4; ++pt)
            bf[kc][pt] = *reinterpret_cast<const bf16x8*>(xr + (size_t)pt*16*256 + kc*32);

    __syncthreads();

    f32x4 acc[4][4];
    #pragma unroll
    for (int i = 0; i < 4; ++i)
        #pragma unroll
        for (int j = 0; j < 4; ++j) acc[i][j] = (f32x4){0.f, 0.f, 0.f, 0.f};

    #pragma unroll
    for (int kc = 0; kc < 8; ++kc) {
        #pragma unroll
        for (int ot2 = 0; ot2 < 4; ++ot2) {
            int fb = ((kc*4 + ot2)*2)*64 + lane;
            bf16x8 ah = *reinterpret_cast<const bf16x8*>(&wf[fb]);
            bf16x8 al = *reinterpret_cast<const bf16x8*>(&wf[fb + 64]);
            #pragma unroll
            for (int pt = 0; pt < 4; ++pt) {
                acc[ot2][pt] = __builtin_amdgcn_mfma_f32_16x16x32_bf16(ah, bf[kc][pt], acc[ot2][pt], 0, 0, 0);
                acc[ot2][pt] = __builtin_amdgcn_mfma_f32_16x16x32_bf16(al, bf[kc][pt], acc[ot2][pt], 0, 0, 0);
            }
        }
    }
    #pragma unroll
    for (int ot2 = 0; ot2 < 4; ++ot2) {
        int o_l = ot2*16 + quad*4;
        int og  = o_base + o_l;
        float b0 = bias[og], b1 = bias[og+1], b2 = bias[og+2], b3 = bias[og+3];
        #pragma unroll
        for (int pt = 0; pt < 4; ++pt) {
            f32x4 a = acc[ot2][pt];
            int px = p0 + wid*64 + pt*16 + n;
            u32 w0 = (u32)f2b(a[0] + b0) | ((u32)f2b(a[1] + b1) << 16);
            u32 w1 = (u32)f2b(a[2] + b2) | ((u32)f2b(a[3] + b3) << 16);
            u16* dst;
            if (ot == 0) dst = pqk + ((size_t)(b*16384 + px))*64  + o_l;
            else         dst = pvx + ((size_t)(b*16384 + px))*256 + (o_base - 64 + o_l);
            *reinterpret_cast<uint2*>(dst) = make_uint2(w0, w1);
        }
    }
}

// ---------------------------------------------------------------------------
// K2: deformed bilinear sampling for batch 0.
// ---------------------------------------------------------------------------
__global__ __launch_bounds__(320) void k_sample(
    const u16* __restrict__ pqk, const u16* __restrict__ pvx,
    const float* __restrict__ dX, const float* __restrict__ dY,
    u16* __restrict__ qdH, u16* __restrict__ pkc, u16* __restrict__ pvc,
    u16* __restrict__ qdW, u16* __restrict__ kdW, u16* __restrict__ vdW)
{
    int bid = blockIdx.x;
    int variant = bid >> 14;
    int pt = bid & 16383;
    int t = threadIdx.x;
    int w, h;
    float xn, yn;
    if (variant == 0) {
        w = pt >> 7; h = pt & 127;
        xn = (-1.0f + (float)w     * (2.0f/128.0f)) + dX[(h+1)*2 + 0];
        yn = (-1.0f + (float)(h+1) * (2.0f/128.0f)) + dX[(h+1)*2 + 1];
    } else {
        h = pt >> 7; w = pt & 127;
        xn = (-1.0f + (float)(w+1) * (2.0f/128.0f)) + dY[(w+1)*2 + 0];
        yn = (-1.0f + (float)h     * (2.0f/128.0f)) + dY[(w+1)*2 + 1];
    }
    float fx = (xn + 1.0f) * 0.5f * 127.0f;
    float fy = (yn + 1.0f) * 0.5f * 127.0f;
    float x0f = floorf(fx), y0f = floorf(fy);
    float wx = fx - x0f, wy = fy - y0f;

    float wt[4]; int xi[4], yi[4]; bool vd[4];
    {
        float xs[2]  = { x0f, x0f + 1.0f };
        float ys[2]  = { y0f, y0f + 1.0f };
        float wxs[2] = { 1.0f - wx, wx };
        float wys[2] = { 1.0f - wy, wy };
        #pragma unroll
        for (int jy = 0; jy < 2; ++jy)
            #pragma unroll
            for (int jx = 0; jx < 2; ++jx) {
                int k = jy*2 + jx;
                vd[k] = (xs[jx] >= 0.f) && (xs[jx] < 128.f) && (ys[jy] >= 0.f) && (ys[jy] < 128.f);
                wt[k] = wxs[jx] * wys[jy];
                xi[k] = (int)fminf(fmaxf(xs[jx], 0.f), 127.f);
                yi[k] = (int)fminf(fmaxf(ys[jy], 0.f), 127.f);
            }
    }
    float val = 0.f;
    if (t < 64) {
        #pragma unroll
        for (int k = 0; k < 4; ++k)
            if (vd[k]) val += wt[k] * b2f(pqk[(size_t)(yi[k]*128 + xi[k])*64 + t]);
        if (t < 32) {
            if (variant == 0) qdH[(size_t)pt*32 + t] = f2b(val);
            else              qdW[(size_t)pt*32 + t] = f2b(val);
        } else {
            int c = t - 32;
            if (variant == 0) pkc[(size_t)pt*32 + c] = f2b(val);
            else              kdW[(size_t)pt*32 + c] = f2b(val);
        }
    } else {
        int c = t - 64;
        #pragma unroll
        for (int k = 0; k < 4; ++k)
            if (vd[k]) val += wt[k] * b2f(pvx[(size_t)(yi[k]*128 + xi[k])*256 + c]);
        if (variant == 0) pvc[(size_t)pt*256 + c] = f2b(val);
        else              vdW[(size_t)pt*256 + c] = f2b(val);
    }
}

// ---------------------------------------------------------------------------
// K3a: raw attention scores via MFMA.  1024 blocks = kind(2) x b(4) x line(128).
// ---------------------------------------------------------------------------
__global__ __launch_bounds__(256) void k_scores(
    const u16* __restrict__ pqk, const u16* __restrict__ pkc,
    const u16* __restrict__ qdH, const u16* __restrict__ qdW, const u16* __restrict__ kdW,
    float* __restrict__ SH, float* __restrict__ SWa, float* __restrict__ SWb)
{
    int bid = blockIdx.x;
    int kind = bid >> 9;
    int b    = (bid >> 7) & 3;
    int line = bid & 127;
    int t = threadIdx.x;
    int wid = t >> 6, lane = t & 63;
    int n16 = lane & 15, quad = lane >> 4;

    const u16 *Qb, *Kb; int qstride, kstride;
    float* Sb = nullptr;
    float* s_lo = nullptr; float* s_hi = nullptr;
    if (kind == 0) {                 // column scores, line = w
        if (b == 0) { Qb = qdH + (size_t)line*4096;                 qstride = 32;
                      Kb = pkc + (size_t)line*4096;                 kstride = 32;   }
        else        { Qb = pqk + ((size_t)(b*16384 + line))*64;     qstride = 8192;
                      Kb = Qb + 32;                                 kstride = 8192; }
        Sb = SH + ((size_t)(b*128 + line))*16384;
    } else {                          // row scores, line = h
        if (b == 0) { Qb = qdW + (size_t)line*4096;                 qstride = 32;
                      Kb = kdW + (size_t)line*4096;                 kstride = 32; }
        else        { Qb = pqk + ((size_t)(b*16384 + line*128))*64; qstride = 64;
                      Kb = Qb + 32;                                 kstride = 64; }
        size_t base = (size_t)(b*128 + line)*8192;
        s_lo = SWa + base;            // rows 0..63
        s_hi = SWb + base;            // rows 64..127 (index m-64)
    }

    bf16x8 af[2];
    #pragma unroll
    for (int m2 = 0; m2 < 2; ++m2)
        af[m2] = *reinterpret_cast<const bf16x8*>(
            Qb + (size_t)(wid*32 + m2*16 + n16)*qstride + quad*8);

    #pragma unroll
    for (int nt = 0; nt < 8; ++nt) {
        bf16x8 bf = *reinterpret_cast<const bf16x8*>(
            Kb + (size_t)(nt*16 + n16)*kstride + quad*8);
        f32x4 a0 = (f32x4){0.f,0.f,0.f,0.f};
        f32x4 a1 = (f32x4){0.f,0.f,0.f,0.f};
        a0 = __builtin_amdgcn_mfma_f32_16x16x32_bf16(af[0], bf, a0, 0, 0, 0);
        a1 = __builtin_amdgcn_mfma_f32_16x16x32_bf16(af[1], bf, a1, 0, 0, 0);
        int j = nt*16 + n16;
        int m0 = wid*32 + quad*4;
        if (kind == 0) {
            #pragma unroll
            for (int r = 0; r < 4; ++r) {
                Sb[(size_t)(m0 + r)*128 + j]      = a0[r];
                Sb[(size_t)(m0 + 16 + r)*128 + j] = a1[r];
            }
        } else {
            #pragma unroll
            for (int r = 0; r < 4; ++r) {
                int mA = m0 + r, mB = m0 + 16 + r;
                float* pA = (mA < 64) ? (s_lo + (size_t)mA*128 + j)
                                      : (s_hi + (size_t)(mA - 64)*128 + j);
                float* pB = (mB < 64) ? (s_lo + (size_t)mB*128 + j)
                                      : (s_hi + (size_t)(mB - 64)*128 + j);
                *pA = a0[r];
                *pB = a1[r];
            }
        }
    }
}

// ---------------------------------------------------------------------------
// K3b: joint softmax, register-resident.  block (b,h), 256 thr = (kind, w).
// ---------------------------------------------------------------------------
__global__ __launch_bounds__(256) void k_softmax(
    const float* __restrict__ SH, const float* __restrict__ SWa, const float* __restrict__ SWb,
    u16* __restrict__ attbH, u16* __restrict__ attbW)
{
    int b = blockIdx.x >> 7, h = blockIdx.x & 127;
    int t = threadIdx.x;
    int kind = t >> 7, w = t & 127;
    __shared__ float mh[256], zh[256];
    __shared__ float Mw[128], Iw[128];

    const float* src;
    if (kind == 0) {
        src = SH + (((size_t)(b*128 + w))*128 + h)*128;
    } else {
        size_t base = (size_t)(b*128 + h)*8192;
        src = (w < 64) ? (SWa + base + (size_t)w*128)
                       : (SWb + base + (size_t)(w - 64)*128);
    }
    const float4* s4 = reinterpret_cast<const float4*>(src);

    float4 row[32];
    #pragma unroll
    for (int q = 0; q < 32; ++q) row[q] = s4[q];

    if (kind == 0) {
        #pragma unroll
        for (int q = 0; q < 32; ++q) {
            float4 v = row[q];
            if (q*4     == h) v.x = -INFINITY;
            if (q*4 + 1 == h) v.y = -INFINITY;
            if (q*4 + 2 == h) v.z = -INFINITY;
            if (q*4 + 3 == h) v.w = -INFINITY;
            row[q] = v;
        }
    }

    float m = -INFINITY;
    #pragma unroll
    for (int q = 0; q < 32; ++q) {
        float4 v = row[q];
        m = fmaxf(m, fmaxf(fmaxf(v.x, v.y), fmaxf(v.z, v.w)));
    }
    mh[t] = m;
    __syncthreads();
    if (t < 128) Mw[t] = fmaxf(mh[t], mh[128 + t]);
    __syncthreads();

    float M = Mw[w];
    float Z = 0.f;
    #pragma unroll
    for (int q = 0; q < 32; ++q) {
        float4 v = row[q];
        Z += __expf(v.x - M) + __expf(v.y - M) + __expf(v.z - M) + __expf(v.w - M);
    }
    zh[t] = Z;
    __syncthreads();
    if (t < 128) Iw[t] = 1.0f / (zh[t] + zh[128 + t]);
    __syncthreads();

    float I = Iw[w];
    u16* dst = (kind == 0)
        ? attbH + (((size_t)(b*128 + h))*128 + w)*128
        : attbW + (((size_t)(b*128 + h))*128 + w)*128;
    #pragma unroll
    for (int q = 0; q < 16; ++q) {
        float4 v0 = row[2*q], v1 = row[2*q + 1];
        u32 o0 = (u32)f2b(__expf(v0.x - M) * I) | ((u32)f2b(__expf(v0.y - M) * I) << 16);
        u32 o1 = (u32)f2b(__expf(v0.z - M) * I) | ((u32)f2b(__expf(v0.w - M) * I) << 16);
        u32 o2 = (u32)f2b(__expf(v1.x - M) * I) | ((u32)f2b(__expf(v1.y - M) * I) << 16);
        u32 o3 = (u32)f2b(__expf(v1.z - M) * I) | ((u32)f2b(__expf(v1.w - M) * I) << 16);
        *reinterpret_cast<uint4*>(dst + q*8) = make_uint4(o0, o1, o2, o3);
    }
}

// ---------------------------------------------------------------------------
// LDS V-transpose staging shared by K4/K5:
// vt[c][m] = pack(V[row 2m][c], V[row 2m+1][c]) as u32, LDS row stride 68 u32.
// vstride = u16 distance between consecutive V rows in global memory.
// ---------------------------------------------------------------------------
__device__ __forceinline__ void stage_vt(u32* vt, const u16* Vsrc, size_t vstride, int t)
{
    int j2 = t & 63;                 // row pair index
    int c8 = (t >> 6) * 8;           // col octet base
    const u16* r0 = Vsrc + (size_t)(2*j2)*vstride;
    const u16* r1 = r0 + vstride;
    #pragma unroll
    for (int i = 0; i < 4; ++i) {
        int c = i*32 + c8;
        uint4 a  = *reinterpret_cast<const uint4*>(r0 + c);
        uint4 bb = *reinterpret_cast<const uint4*>(r1 + c);
        u32 au[4] = {a.x, a.y, a.z, a.w};
        u32 bu[4] = {bb.x, bb.y, bb.z, bb.w};
        #pragma unroll
        for (int e = 0; e < 4; ++e) {
            vt[(c + 2*e    )*68 + j2] = (au[e] & 0xffffu) | (bu[e] << 16);
            vt[(c + 2*e + 1)*68 + j2] = (au[e] >> 16)     | (bu[e] & 0xffff0000u);
        }
    }
}

// ---------------------------------------------------------------------------
// K4: column aggregation via MFMA, V via LDS transpose.
// T[b][w][k][c] = sum_h att * V;  V from pvc slab (b=0) or pvx columns (b>=1).
// ---------------------------------------------------------------------------
__global__ __launch_bounds__(256, 2) void k_outcol(const u16* __restrict__ pvc,
    const u16* __restrict__ pvx, const u16* __restrict__ attbH, u16* __restrict__ T)
{
    int b = blockIdx.x >> 7, w = blockIdx.x & 127;
    int half = blockIdx.y;
    int t = threadIdx.x;
    int wid = t >> 6, lane = t & 63;
    int n16 = lane & 15, quad = lane >> 4;

    __shared__ u32 vt[128*68];

    const u16* Abase = attbH + ((size_t)b*128)*16384 + (size_t)w*128;
    bf16x8 af[2][4];
    #pragma unroll
    for (int m2 = 0; m2 < 2; ++m2)
        #pragma unroll
        for (int ks = 0; ks < 4; ++ks)
            af[m2][ks] = *reinterpret_cast<const bf16x8*>(
                Abase + (size_t)(wid*32 + m2*16 + n16)*16384 + ks*32 + quad*8);

    if (b == 0)
        stage_vt(vt, pvc + (size_t)w*128*256 + half*128, 256, t);
    else
        stage_vt(vt, pvx + ((size_t)(b*16384 + w))*256 + half*128, 32768, t);
    __syncthreads();

    f32x4 acc[2][8];
    #pragma unroll
    for (int m2 = 0; m2 < 2; ++m2)
        #pragma unroll
        for (int nt = 0; nt < 8; ++nt) acc[m2][nt] = (f32x4){0.f,0.f,0.f,0.f};

    #pragma unroll
    for (int nt = 0; nt < 8; ++nt) {
        int c = nt*16 + n16;
        #pragma unroll
        for (int ks = 0; ks < 4; ++ks) {
            bf16x8 bfv = *reinterpret_cast<const bf16x8*>(&vt[c*68 + ks*16 + quad*4]);
            acc[0][nt] = __builtin_amdgcn_mfma_f32_16x16x32_bf16(af[0][ks], bfv, acc[0][nt], 0, 0, 0);
            acc[1][nt] = __builtin_amdgcn_mfma_f32_16x16x32_bf16(af[1][ks], bfv, acc[1][nt], 0, 0, 0);
        }
    }

    u16* Tbase = T + (((size_t)(b*128 + w))*128)*256 + half*128;
    #pragma unroll
    for (int m2 = 0; m2 < 2; ++m2) {
        int k0 = wid*32 + m2*16 + quad*4;
        #pragma unroll
        for (int nt = 0; nt < 8; ++nt) {
            int c = nt*16 + n16;
            f32x4 a = acc[m2][nt];
            #pragma unroll
            for (int r = 0; r < 4; ++r)
                Tbase[(size_t)(k0 + r)*256 + c] = f2b(a[r]);
        }
    }
}

// ---------------------------------------------------------------------------
// K5: row aggregation via MFMA + epilogue, V via LDS transpose.
// ---------------------------------------------------------------------------
__global__ __launch_bounds__(256, 2) void k_outrow(const u16* __restrict__ pvx, const u16* __restrict__ vdW,
    const u16* __restrict__ attbW, const u16* __restrict__ T, const void* __restrict__ xraw,
    const void* __restrict__ gamma, void* __restrict__ out, const int* __restrict__ flag)
{
    bool f32 = flag[0] != 0;
    int b = blockIdx.x >> 7, h = blockIdx.x & 127;
    int half = blockIdx.y;
    int t = threadIdx.x;
    int wid = t >> 6, lane = t & 63;
    int n16 = lane & 15, quad = lane >> 4;

    __shared__ u32 vt[128*68];

    const u16* Abase = attbW + ((size_t)(b*128 + h))*16384;
    bf16x8 af[2][4];
    #pragma unroll
    for (int m2 = 0; m2 < 2; ++m2)
        #pragma unroll
        for (int ks = 0; ks < 4; ++ks)
            af[m2][ks] = *reinterpret_cast<const bf16x8*>(
                Abase + (size_t)(wid*32 + m2*16 + n16)*128 + ks*32 + quad*8);

    const u16* Vsrc = ((b == 0) ? (vdW + (size_t)h*128*256)
                                : (pvx + ((size_t)b*16384 + h*128)*256)) + half*128;
    stage_vt(vt, Vsrc, 256, t);
    __syncthreads();

    f32x4 acc[2][8];
    #pragma unroll
    for (int m2 = 0; m2 < 2; ++m2)
        #pragma unroll
        for (int nt = 0; nt < 8; ++nt) acc[m2][nt] = (f32x4){0.f,0.f,0.f,0.f};

    #pragma unroll
    for (int nt = 0; nt < 8; ++nt) {
        int c = nt*16 + n16;
        #pragma unroll
        for (int ks = 0; ks < 4; ++ks) {
            bf16x8 bfv = *reinterpret_cast<const bf16x8*>(&vt[c*68 + ks*16 + quad*4]);
            acc[0][nt] = __builtin_amdgcn_mfma_f32_16x16x32_bf16(af[0][ks], bfv, acc[0][nt], 0, 0, 0);
            acc[1][nt] = __builtin_amdgcn_mfma_f32_16x16x32_bf16(af[1][ks], bfv, acc[1][nt], 0, 0, 0);
        }
    }

    float gm = ldin(gamma, 0, f32);
    const u16* Tbase = T + ((size_t)(b*128))*128*256 + (size_t)h*256 + half*128;

    #pragma unroll
    for (int m2 = 0; m2 < 2; ++m2) {
        int k0 = wid*32 + m2*16 + quad*4;
        #pragma unroll
        for (int nt = 0; nt < 8; ++nt) {
            int c = nt*16 + n16;
            int cg = half*128 + c;
            f32x4 a = acc[m2][nt];
            float r[4];
            #pragma unroll
            for (int i = 0; i < 4; ++i) {
                float hst = b2f(Tbase[(size_t)(k0 + i)*32768 + c]);
                r[i] = gm * (hst + a[i]);
            }
            size_t base = ((size_t)(b*256 + cg)*128 + h)*128 + k0;
            if (f32) {
                float4 xx = *reinterpret_cast<const float4*>((const float*)xraw + base);
                float4 rr;
                rr.x = r[0] + xx.x; rr.y = r[1] + xx.y;
                rr.z = r[2] + xx.z; rr.w = r[3] + xx.w;
                if (!(rr.x == rr.x)) rr.x = -299.f;
                if (!(rr.y == rr.y)) rr.y = -299.f;
                if (!(rr.z == rr.z)) rr.z = -299.f;
                if (!(rr.w == rr.w)) rr.w = -299.f;
                *reinterpret_cast<float4*>((float*)out + base) = rr;
            } else {
                uint2 xx = *reinterpret_cast<const uint2*>((const u16*)xraw + base);
                u32 xu[2] = { xx.x, xx.y };
                u32 ou[2];
                #pragma unroll
                for (int p2 = 0; p2 < 2; ++p2) {
                    float xlo = __uint_as_float(xu[p2] << 16);
                    float xhi = __uint_as_float(xu[p2] & 0xffff0000u);
                    float olo = r[p2*2]   + xlo;
                    float ohi = r[p2*2+1] + xhi;
                    if (!(olo == olo)) olo = -299.f;
                    if (!(ohi == ohi)) ohi = -299.f;
                    ou[p2] = (u32)f2b(olo) | ((u32)f2b(ohi) << 16);
                }
                *reinterpret_cast<uint2*>((u16*)out + base) = make_uint2(ou[0], ou[1]);
            }
        }
    }
}

// ---------------------------------------------------------------------------
extern "C" void kernel_launch(void* const* d_in, const int* in_sizes, int n_in,
                              void* d_out, int out_size, void* d_ws, size_t ws_size,
                              hipStream_t stream)
{
    const void* x     = d_in[0];
    const void* Wq    = d_in[1];
    const void* bq    = d_in[2];
    const void* Wk    = d_in[3];
    const void* bk    = d_in[4];
    const void* Wv    = d_in[5];
    const void* bv    = d_in[6];
    const void* gamma = d_in[7];
    const void* off   = d_in[8];

    char* ws = (char*)d_ws;
    size_t o = 0;
    auto alloc = [&](size_t bytes) { size_t r = o; o += (bytes + 255) & ~(size_t)255; return r; };
    int*   flag = (int*)(ws + alloc(256));
    float* dX   = (float*)(ws + alloc(129*2*4));
    float* dY   = (float*)(ws + alloc(129*2*4));
    float* part = (float*)(ws + alloc(64*4));
    u16*   pqk  = (u16*)(ws + alloc((size_t)4*16384*64*2));     // [B][HW][64]
    u16*   pvx  = (u16*)(ws + alloc((size_t)4*16384*256*2));    // [B][HW][256]
    u16*   pkc  = (u16*)(ws + alloc((size_t)16384*32*2));       // b=0 deformed K slab only
    u16*   pvc  = (u16*)(ws + alloc((size_t)16384*256*2));      // b=0 deformed V slab only
    u16*   qdH  = (u16*)(ws + alloc((size_t)16384*32*2));
    u16*   qdW  = (u16*)(ws + alloc((size_t)16384*32*2));
    u16*   kdW  = (u16*)(ws + alloc((size_t)16384*32*2));
    u16*   vdW  = (u16*)(ws + alloc((size_t)16384*256*2));      // [H][W][256]
    u16*   attbH= (u16*)(ws + alloc((size_t)4*128*128*128*2));  // [B][H][W][128]
    u16*   attbW= (u16*)(ws + alloc((size_t)4*128*128*128*2));
    u16*   T    = (u16*)(ws + alloc((size_t)4*128*128*256*2));  // [B][W][Hout][C] bf16
    u16*   WH   = (u16*)(ws + alloc((size_t)320*256*2));        // weight hi bf16
    u16*   WLo  = (u16*)(ws + alloc((size_t)320*256*2));        // weight lo bf16
    float* bias = (float*)(ws + alloc(320*4));
    // aliases (all within the workspace; d_out is NEVER used as scratch):
    u16*   xb   = T;                       // xb dead after k_proj_mfma; T written by k_outcol
    float* SH   = (float*)T;               // SH [B][W][H][128] f32 == 33.5 MB == sizeof(T)
    float* SWa  = (float*)attbH;           // SW rows w<64  live inside attbH bytes (f32)
    float* SWb  = (float*)attbW;           // SW rows w>=64 live inside attbW bytes (f32)

    k_detect   <<<1, 256, 0, stream>>>(x, flag);
    k_setup_red<<<65, 256, 0, stream>>>(off, dX, dY, part, flag);
    k_setup_fin<<<1, 64, 0, stream>>>(part, d_out, flag);
    k_wconv    <<<320, 256, 0, stream>>>(Wq, Wk, Wv, bq, bk, bv, WH, WLo, bias, flag);
    k_xconv    <<<1024, 256, 0, stream>>>(x, xb, flag);
    k_proj_mfma<<<1280, 256, 0, stream>>>(xb, WH, WLo, bias, pqk, pvx);
    k_sample   <<<32768, 320, 0, stream>>>(pqk, pvx, dX, dY, qdH, pkc, pvc, qdW, kdW, vdW);
    k_scores   <<<1024, 256, 0, stream>>>(pqk, pkc, qdH, qdW, kdW, SH, SWa, SWb);
    k_softmax  <<<512, 256, 0, stream>>>(SH, SWa, SWb, attbH, attbW);
    k_outcol   <<<dim3(512, 2), 256, 0, stream>>>(pvc, pvx, attbH, T);
    k_outrow   <<<dim3(512, 2), 256, 0, stream>>>(pvx, vdW, attbW, T, x, gamma, d_out, flag);
    (void)in_sizes; (void)n_in; (void)out_size; (void)ws_size;
}